// Round 2
// baseline (522.622 us; speedup 1.0000x reference)
//
#include <hip/hip_runtime.h>
#include <hip/hip_bf16.h>
#include <math.h>

// Problem constants (B=16, N=1024, D=256, F=1024, H=8, hd=32)
#define Bq 16
#define Nq 1024
#define Dq 256
#define Fq 1024
#define Hq 8
#define HDq 32
#define Mq (Bq * Nq)          // 16384 rows
#define SCALE 0.0625f          // D^-0.5 = 1/16
#define LN_EPS 1e-5f

typedef __attribute__((ext_vector_type(8))) short short8;   // 8 bf16
typedef __attribute__((ext_vector_type(4))) float f32x4;

__device__ __forceinline__ float bf2f(unsigned short s) {
    unsigned u = ((unsigned)s) << 16;
    return __builtin_bit_cast(float, u);
}
__device__ __forceinline__ unsigned short f2bf(float f) {
    __hip_bfloat16 h = __float2bfloat16(f);
    return __builtin_bit_cast(unsigned short, h);
}

// async global->LDS, 16B per lane (lands at ldsbase + lane*16)
typedef __attribute__((address_space(3))) unsigned int lds_uint;
typedef const __attribute__((address_space(1))) unsigned int glb_uint;
__device__ __forceinline__ void async16(void* lds, const void* g) {
    __builtin_amdgcn_global_load_lds((glb_uint*)g, (lds_uint*)lds, 16, 0, 0);
}

__device__ __forceinline__ float gelu_tanh(float v) {
    const float c = 0.7978845608028654f;
    float u = c * (v + 0.044715f * v * v * v);
    return 0.5f * v * (1.0f + tanhf(u));
}

// ---------------------------------------------------------------------------
// Kernel 0: convert the 6 weight matrices to bf16 (Wq,Wk,Wv rows 0..767 of W16)
// ---------------------------------------------------------------------------
__global__ __launch_bounds__(256) void cvt_weights(
    const float* __restrict__ Wq, const float* __restrict__ Wk,
    const float* __restrict__ Wv, const float* __restrict__ Wo,
    const float* __restrict__ W1, const float* __restrict__ W2,
    unsigned short* __restrict__ dst)
{
    const int blk = blockIdx.x;
    int seg, local;
    if (blk < 256)      { seg = blk >> 6; local = blk & 63; }
    else if (blk < 512) { seg = 4; local = blk - 256; }
    else                { seg = 5; local = blk - 512; }
    const float* srcs[6] = {Wq, Wk, Wv, Wo, W1, W2};
    const size_t dsto[6] = {0, 65536, 131072, 196608, 262144, 524288};
    const float* src = srcs[seg] + (size_t)local * 1024;
    unsigned short* d = dst + dsto[seg] + (size_t)local * 1024;
    const int t4 = threadIdx.x * 4;
    float4 v = *(const float4*)(src + t4);
    uint2 o;
    o.x = (unsigned)f2bf(v.x) | ((unsigned)f2bf(v.y) << 16);
    o.y = (unsigned)f2bf(v.z) | ((unsigned)f2bf(v.w) << 16);
    *(uint2*)(d + t4) = o;
}

// ---------------------------------------------------------------------------
// Kernel 0b: bias16 = bf16(sp + ed), pure streaming (134 MB rd, 33.5 MB wr).
// Runs at full HBM BW because it has no compute/serialization phase.
// ---------------------------------------------------------------------------
__global__ __launch_bounds__(256) void bias_cvt(
    const float* __restrict__ sp, const float* __restrict__ ed,
    unsigned short* __restrict__ dst)
{
    const size_t i = ((size_t)blockIdx.x * 256 + threadIdx.x) * 8;
    float4 a0 = *(const float4*)(sp + i);
    float4 a1 = *(const float4*)(sp + i + 4);
    float4 e0 = *(const float4*)(ed + i);
    float4 e1 = *(const float4*)(ed + i + 4);
    uint4 o;
    o.x = (unsigned)f2bf(a0.x + e0.x) | ((unsigned)f2bf(a0.y + e0.y) << 16);
    o.y = (unsigned)f2bf(a0.z + e0.z) | ((unsigned)f2bf(a0.w + e0.w) << 16);
    o.z = (unsigned)f2bf(a1.x + e1.x) | ((unsigned)f2bf(a1.y + e1.y) << 16);
    o.w = (unsigned)f2bf(a1.z + e1.z) | ((unsigned)f2bf(a1.w + e1.w) << 16);
    *(uint4*)(dst + i) = o;
}

// ---------------------------------------------------------------------------
// Kernel 1: fused double LayerNorm -> bf16 outputs (shared mean/rstd)
// ---------------------------------------------------------------------------
__global__ __launch_bounds__(256) void ln2_kernel(
    const float* __restrict__ x,
    const float* __restrict__ g1, const float* __restrict__ bb1,
    const float* __restrict__ g2, const float* __restrict__ bb2,
    unsigned short* __restrict__ att_in, unsigned short* __restrict__ ffn_in)
{
    const int row = blockIdx.x;
    const int t = threadIdx.x;
    const size_t base = (size_t)row * Dq;
    float v = x[base + t];

    float s = v, sq = v * v;
    #pragma unroll
    for (int off = 32; off > 0; off >>= 1) {
        s  += __shfl_down(s, off);
        sq += __shfl_down(sq, off);
    }
    __shared__ float ssum[4], ssq[4];
    __shared__ float mu_s, rstd_s;
    const int lane = t & 63, wid = t >> 6;
    if (lane == 0) { ssum[wid] = s; ssq[wid] = sq; }
    __syncthreads();
    if (t == 0) {
        float S = ssum[0] + ssum[1] + ssum[2] + ssum[3];
        float Q = ssq[0] + ssq[1] + ssq[2] + ssq[3];
        float mu = S * (1.0f / Dq);
        float var = Q * (1.0f / Dq) - mu * mu;
        mu_s = mu;
        rstd_s = rsqrtf(var + LN_EPS);
    }
    __syncthreads();
    const float nx = (v - mu_s) * rstd_s;
    att_in[base + t] = f2bf(nx * g1[t] + bb1[t]);
    ffn_in[base + t] = f2bf(nx * g2[t] + bb2[t]);
}

// ---------------------------------------------------------------------------
// Kernel 2: MFMA NT GEMM  C[M,Nc] = A[M,K] * W[Nc,K]^T  (bf16 in, fp32 acc)
// 128x128 tile, BK=32, operand-swapped (W = A-operand) for vector epilogue.
// mode 0: fp32 out (+bias,+gelu,+add)   [Wo, FFN2]
// mode 1: bf16 flat out (+bias,+gelu)   [FFN1]
// mode 2: merged QKV (Nc=768): Q scaled+head-major, K head-major, V transposed
// ---------------------------------------------------------------------------
#define TM 128
#define TN 128
#define TK 32

__global__ __launch_bounds__(256) void gemm_mfma(
    const unsigned short* __restrict__ A, const unsigned short* __restrict__ W,
    const float* __restrict__ bias, const float* __restrict__ add,
    float* __restrict__ outF, unsigned short* __restrict__ outBF,
    unsigned short* __restrict__ Qb, unsigned short* __restrict__ Kb,
    unsigned short* __restrict__ Vt,
    int M, int Nc, int K, int mode, int apply_gelu)
{
    __shared__ unsigned short As[TM * TK];   // 8 KB
    __shared__ unsigned short Bs[TN * TK];   // 8 KB
    const int t = threadIdx.x;
    const int w = t >> 6, lane = t & 63;
    const int col = lane & 15, quad = lane >> 4;
    const int wr = w >> 1, wc = w & 1;
    const int row0 = blockIdx.y * TM;
    const int col0 = blockIdx.x * TN;

    f32x4 acc[4][4] = {};

    for (int k0 = 0; k0 < K; k0 += TK) {
        #pragma unroll
        for (int j = 0; j < 2; j++) {
            const int c = w * 128 + j * 64 + lane;   // chunk 0..511 (16B each)
            const int r = c >> 2, seg = c & 3;
            async16(&As[(size_t)(w * 128 + j * 64) * 8],
                    A + (size_t)(row0 + r) * K + k0 + seg * 8);
            async16(&Bs[(size_t)(w * 128 + j * 64) * 8],
                    W + (size_t)(col0 + r) * K + k0 + seg * 8);
        }
        __syncthreads();   // drains vmcnt (global_load_lds) + barrier
        short8 wf[4], af[4];
        #pragma unroll
        for (int i = 0; i < 4; i++)
            wf[i] = *(const short8*)&Bs[(wc * 64 + i * 16 + col) * TK + quad * 8];
        #pragma unroll
        for (int j = 0; j < 4; j++)
            af[j] = *(const short8*)&As[(wr * 64 + j * 16 + col) * TK + quad * 8];
        // D[c][r]: A-operand = W rows (c), B-operand = A rows (r)
        #pragma unroll
        for (int i = 0; i < 4; i++)
            #pragma unroll
            for (int j = 0; j < 4; j++)
                acc[i][j] = __builtin_amdgcn_mfma_f32_16x16x32_bf16(wf[i], af[j], acc[i][j], 0, 0, 0);
        __syncthreads();
    }

    // epilogue: lane owns cols c0..c0+3 (consecutive), output row r
    #pragma unroll
    for (int i = 0; i < 4; i++) {
        #pragma unroll
        for (int j = 0; j < 4; j++) {
            const int c0 = col0 + wc * 64 + i * 16 + quad * 4;
            const int r  = row0 + wr * 64 + j * 16 + col;
            float4 v = make_float4(acc[i][j][0], acc[i][j][1], acc[i][j][2], acc[i][j][3]);
            if (mode == 2 && c0 < 256) { v.x *= SCALE; v.y *= SCALE; v.z *= SCALE; v.w *= SCALE; }
            if (bias) {
                float4 bb = *(const float4*)&bias[c0];
                v.x += bb.x; v.y += bb.y; v.z += bb.z; v.w += bb.w;
            }
            if (apply_gelu) {
                v.x = gelu_tanh(v.x); v.y = gelu_tanh(v.y);
                v.z = gelu_tanh(v.z); v.w = gelu_tanh(v.w);
            }
            if (add) {
                float4 aa = *(const float4*)&add[(size_t)r * Nc + c0];
                v.x += aa.x; v.y += aa.y; v.z += aa.z; v.w += aa.w;
            }
            if (mode == 0) {
                *(float4*)&outF[(size_t)r * Nc + c0] = v;
            } else if (mode == 1) {
                uint2 o;
                o.x = (unsigned)f2bf(v.x) | ((unsigned)f2bf(v.y) << 16);
                o.y = (unsigned)f2bf(v.z) | ((unsigned)f2bf(v.w) << 16);
                *(uint2*)&outBF[(size_t)r * Nc + c0] = o;
            } else {
                const int b = r >> 10, n = r & 1023;
                if (c0 < 512) {
                    // Q (c0<256, pre-scaled) or K: head-major [B,H,N,32]
                    const int cq = c0 & 255;
                    const int h = cq >> 5, d0 = cq & 31;
                    unsigned short* dst = (c0 < 256 ? Qb : Kb);
                    uint2 o;
                    o.x = (unsigned)f2bf(v.x) | ((unsigned)f2bf(v.y) << 16);
                    o.y = (unsigned)f2bf(v.z) | ((unsigned)f2bf(v.w) << 16);
                    *(uint2*)&dst[(((size_t)(b * Hq + h) << 10) + n) * HDq + d0] = o;
                } else {
                    // V transposed: Vt[B,H,32,N]
                    const int cv = c0 - 512;
                    const int h = cv >> 5, d0 = cv & 31;
                    unsigned short* dst = Vt + (((size_t)(b * Hq + h) * HDq + d0) << 10) + n;
                    dst[0]      = f2bf(v.x);
                    dst[1024]   = f2bf(v.y);
                    dst[2048]   = f2bf(v.z);
                    dst[3072]   = f2bf(v.w);
                }
            }
        }
    }
}

// ---------------------------------------------------------------------------
// Kernel 3: MFMA attention, wave-autonomous flash-style, ZERO barriers.
// Block = (b, 16 q-rows), 512 threads = 8 waves, wave w == head w.
// Bias is pre-converted bf16 (bias_cvt) read directly from global: the block's
// 32 KB slice is shared by all 8 waves via L1/L2, so no staging phase and no
// barrier at all. LDS = 32 KB (per-wave S-tiles only) -> 4 blocks/CU =
// 32 waves/CU (100% occupancy, launch_bounds(512,8) caps VGPR at 64).
// Per wave, per 128-key tile: 8x QK^T MFMA -> +bias, exp -> 4KB swizzled
// per-wave S-tile -> 8x PV MFMA. Row sums live in registers (rsum[i] row
// mapping quad*4+i equals PV C-layout rows), shfl_xor(16) reduce at end.
// S-tile XOR swizzle (short idx ^= (row&7)<<3): conflict-free b128 PV reads.
// ---------------------------------------------------------------------------
__global__ __launch_bounds__(512, 8) void attn_mfma(
    const unsigned short* __restrict__ Qbf, const unsigned short* __restrict__ Kbf,
    const unsigned short* __restrict__ Vt, const unsigned short* __restrict__ biasg,
    unsigned short* __restrict__ O16)
{
    const int b = blockIdx.y;
    const int n0 = blockIdx.x * 16;
    const int t = threadIdx.x;
    const int h = t >> 6;            // wave index == head
    const int lane = t & 63;
    const int col = lane & 15;
    const int quad = lane >> 4;

    __shared__ unsigned short S16[8][16 * 128];    // 32 KB, 4KB per wave

    const size_t hb = (size_t)b * Hq + h;
    const unsigned short* Qh = Qbf + hb * (Nq * HDq);
    const unsigned short* Kh = Kbf + hb * (Nq * HDq);
    const unsigned short* Vh = Vt  + hb * (HDq * Nq);
    const unsigned short* bg = biasg + (((size_t)b * Nq + n0) << 10);  // [16][1024]
    unsigned short* Sw = &S16[h][0];

    // A-frag: Q rows n0..n0+15 (pre-scaled by 1/16 in gemm epilogue)
    const short8 aq = *(const short8*)(Qh + (size_t)(n0 + col) * HDq + quad * 8);

    f32x4 o0 = {0.f, 0.f, 0.f, 0.f}, o1 = {0.f, 0.f, 0.f, 0.f};
    float rsum[4] = {0.f, 0.f, 0.f, 0.f};

    for (int tt = 0; tt < 8; tt++) {                   // 128-key flash tiles
        const int k0 = tt * 128;
        // ---- QK^T + bias + exp -> per-wave swizzled S-tile
        #pragma unroll
        for (int m = 0; m < 8; m++) {
            const int m0 = k0 + m * 16;
            short8 bk = *(const short8*)(Kh + (size_t)(m0 + col) * HDq + quad * 8);
            f32x4 cc = {0.f, 0.f, 0.f, 0.f};
            cc = __builtin_amdgcn_mfma_f32_16x16x32_bf16(aq, bk, cc, 0, 0, 0);
            #pragma unroll
            for (int i = 0; i < 4; i++) {
                const int r = quad * 4 + i;
                float s = cc[i] + bf2f(bg[(size_t)r * Nq + m0 + col]);
                float e = __expf(s);
                rsum[i] += e;
                const int sidx = (r * 128 + m * 16 + col) ^ ((r & 7) << 3);
                Sw[sidx] = f2bf(e);
            }
        }
        // ---- PV: S-tile (16x128) @ V^T-rows, accumulate (same-wave LDS RAW:
        //      compiler inserts lgkmcnt waits; no barrier needed)
        #pragma unroll
        for (int c = 0; c < 4; c++) {
            const int ridx = (col * 128 + c * 32 + quad * 8) ^ ((col & 7) << 3);
            short8 ap  = *(const short8*)&Sw[ridx];
            short8 bv0 = *(const short8*)(Vh + (size_t)col * Nq + k0 + c * 32 + quad * 8);
            short8 bv1 = *(const short8*)(Vh + (size_t)(col + 16) * Nq + k0 + c * 32 + quad * 8);
            o0 = __builtin_amdgcn_mfma_f32_16x16x32_bf16(ap, bv0, o0, 0, 0, 0);
            o1 = __builtin_amdgcn_mfma_f32_16x16x32_bf16(ap, bv1, o1, 0, 0, 0);
        }
    }

    // ---- in-register row-sum reduce across the 16 col-lanes of each quad
    #pragma unroll
    for (int off = 1; off < 16; off <<= 1) {
        #pragma unroll
        for (int i = 0; i < 4; i++) rsum[i] += __shfl_xor(rsum[i], off, 16);
    }

    // ---- normalize + store: lane owns rows quad*4+i, cols col / col+16
    unsigned short* op = O16 + ((size_t)b * Nq + n0) * Dq + h * HDq;
    #pragma unroll
    for (int i = 0; i < 4; i++) {
        const float inv = 1.0f / rsum[i];
        const int q = quad * 4 + i;
        op[(size_t)q * Dq + col]      = f2bf(o0[i] * inv);
        op[(size_t)q * Dq + col + 16] = f2bf(o1[i] * inv);
    }
}

// ---------------------------------------------------------------------------
// Kernel 4: pad_mask2 — zero rows of out where att_output has any exact 0
// ---------------------------------------------------------------------------
__global__ __launch_bounds__(256) void pad2_kernel(
    const float* __restrict__ AO, float* __restrict__ out)
{
    const int row = blockIdx.x;
    const int t = threadIdx.x;
    const float v = AO[(size_t)row * Dq + t];
    unsigned long long m = __ballot(v == 0.0f);
    __shared__ unsigned long long w[4];
    if ((t & 63) == 0) w[t >> 6] = m;
    __syncthreads();
    if ((w[0] | w[1] | w[2] | w[3]) != 0ULL)
        out[(size_t)row * Dq + t] = 0.0f;
}

// ---------------------------------------------------------------------------
extern "C" void kernel_launch(void* const* d_in, const int* in_sizes, int n_in,
                              void* d_out, int out_size, void* d_ws, size_t ws_size,
                              hipStream_t stream)
{
    const float* x      = (const float*)d_in[0];
    const float* sp     = (const float*)d_in[1];
    const float* ed     = (const float*)d_in[2];
    const float* gamma1 = (const float*)d_in[3];
    const float* beta1  = (const float*)d_in[4];
    const float* gamma2 = (const float*)d_in[5];
    const float* beta2  = (const float*)d_in[6];
    const float* Wq     = (const float*)d_in[7];
    const float* Wk     = (const float*)d_in[8];
    const float* Wv     = (const float*)d_in[9];
    const float* Wo     = (const float*)d_in[10];
    const float* W1     = (const float*)d_in[11];
    const float* b1     = (const float*)d_in[12];
    const float* W2     = (const float*)d_in[13];
    const float* b2     = (const float*)d_in[14];
    float* out = (float*)d_out;

    // workspace layout (in shorts)
    unsigned short* s = (unsigned short*)d_ws;
    const size_t MD = (size_t)Mq * Dq;                  // 4.19M elements
    unsigned short* att_in16 = s;                        // [M,D] bf16; reused as O16
    unsigned short* ffn_in16 = s + MD;                   // [M,D] bf16
    unsigned short* Qbf      = s + 2 * MD;               // [B,H,N,32] bf16
    unsigned short* Kbf      = s + 3 * MD;               // [B,H,N,32] bf16
    unsigned short* Vtb      = s + 4 * MD;               // [B,H,32,N] bf16 (transposed)
    unsigned short* W16      = s + 5 * MD;               // 786432 shorts
    unsigned short* h16      = s + 5 * MD + 786432;      // [M,F] bf16 (33.5 MB)
    unsigned short* O16      = att_in16;                 // attn out (att_in dead)
    float*          AO       = (float*)Qbf;              // [M,D] fp32 (Q/K dead)
    // bias16 [B,N,N] bf16 = 16.78M shorts == exactly h16's size; bias16 is
    // dead before FFN1 writes h16 -> alias them (no extra workspace).
    unsigned short* bias16   = h16;

    unsigned short* Wo16 = W16 + 196608;
    unsigned short* W116 = W16 + 262144;
    unsigned short* W216 = W16 + 524288;

    // 0) weights -> bf16 (Wq/Wk/Wv contiguous as rows 0..767 for merged QKV)
    cvt_weights<<<768, 256, 0, stream>>>(Wq, Wk, Wv, Wo, W1, W2, W16);

    // 0b) bias16 = bf16(sp + ed)  (full-BW streaming pass)
    bias_cvt<<<8192, 256, 0, stream>>>(sp, ed, bias16);

    // 1) both layernorms -> bf16
    ln2_kernel<<<Mq, 256, 0, stream>>>(x, gamma1, beta1, gamma2, beta2, att_in16, ffn_in16);

    // 2) merged QKV projection (Q scaled + head-major, K head-major, V transposed)
    dim3 gQKV(768 / TN, Mq / TM);   // (6, 128)
    gemm_mfma<<<gQKV, 256, 0, stream>>>(att_in16, W16, nullptr, nullptr, nullptr, nullptr,
                                        Qbf, Kbf, Vtb, Mq, 768, Dq, 2, 0);

    // 3) MFMA attention: block=(qt,b), 8 waves = 8 heads -> O16 (bf16 [B,N,D])
    attn_mfma<<<dim3(Nq / 16, Bq), 512, 0, stream>>>(Qbf, Kbf, Vtb, bias16, O16);

    // 4) output projection + residual: AO = O @ Wo^T + x   (fp32)
    dim3 gP(Dq / TN, Mq / TM);
    gemm_mfma<<<gP, 256, 0, stream>>>(O16, Wo16, nullptr, x, AO, nullptr,
                                      nullptr, nullptr, nullptr, Mq, Dq, Dq, 0, 0);

    // 5) FFN1: h16 = bf16(gelu(ffn_in @ W1^T + b1))
    dim3 gF1(Fq / TN, Mq / TM);
    gemm_mfma<<<gF1, 256, 0, stream>>>(ffn_in16, W116, b1, nullptr, nullptr, h16,
                                       nullptr, nullptr, nullptr, Mq, Fq, Dq, 1, 1);

    // 6) FFN2: out = h @ W2^T + b2 + AO
    gemm_mfma<<<gP, 256, 0, stream>>>(h16, W216, b2, AO, out, nullptr,
                                      nullptr, nullptr, nullptr, Mq, Dq, Fq, 0, 0);

    // 7) pad_mask2 row zeroing
    pad2_kernel<<<Mq, 256, 0, stream>>>(AO, out);
}

// Round 3
// 489.473 us; speedup vs baseline: 1.0677x; 1.0677x over previous
//
#include <hip/hip_runtime.h>
#include <hip/hip_bf16.h>
#include <math.h>

// Problem constants (B=16, N=1024, D=256, F=1024, H=8, hd=32)
#define Bq 16
#define Nq 1024
#define Dq 256
#define Fq 1024
#define Hq 8
#define HDq 32
#define Mq (Bq * Nq)          // 16384 rows
#define SCALE 0.0625f          // D^-0.5 = 1/16
#define LN_EPS 1e-5f

typedef __attribute__((ext_vector_type(8))) short short8;   // 8 bf16
typedef __attribute__((ext_vector_type(4))) float f32x4;

__device__ __forceinline__ float bf2f(unsigned short s) {
    unsigned u = ((unsigned)s) << 16;
    return __builtin_bit_cast(float, u);
}
__device__ __forceinline__ unsigned short f2bf(float f) {
    __hip_bfloat16 h = __float2bfloat16(f);
    return __builtin_bit_cast(unsigned short, h);
}

// async global->LDS, 16B per lane (lands at ldsbase + lane*16)
typedef __attribute__((address_space(3))) unsigned int lds_uint;
typedef const __attribute__((address_space(1))) unsigned int glb_uint;
__device__ __forceinline__ void async16(void* lds, const void* g) {
    __builtin_amdgcn_global_load_lds((glb_uint*)g, (lds_uint*)lds, 16, 0, 0);
}

__device__ __forceinline__ float gelu_tanh(float v) {
    const float c = 0.7978845608028654f;
    float u = c * (v + 0.044715f * v * v * v);
    return 0.5f * v * (1.0f + tanhf(u));
}

// ---------------------------------------------------------------------------
// Kernel 0: convert the 6 weight matrices to bf16 (Wq,Wk,Wv rows 0..767 of W16)
// ---------------------------------------------------------------------------
__global__ __launch_bounds__(256) void cvt_weights(
    const float* __restrict__ Wq, const float* __restrict__ Wk,
    const float* __restrict__ Wv, const float* __restrict__ Wo,
    const float* __restrict__ W1, const float* __restrict__ W2,
    unsigned short* __restrict__ dst)
{
    const int blk = blockIdx.x;
    int seg, local;
    if (blk < 256)      { seg = blk >> 6; local = blk & 63; }
    else if (blk < 512) { seg = 4; local = blk - 256; }
    else                { seg = 5; local = blk - 512; }
    const float* srcs[6] = {Wq, Wk, Wv, Wo, W1, W2};
    const size_t dsto[6] = {0, 65536, 131072, 196608, 262144, 524288};
    const float* src = srcs[seg] + (size_t)local * 1024;
    unsigned short* d = dst + dsto[seg] + (size_t)local * 1024;
    const int t4 = threadIdx.x * 4;
    float4 v = *(const float4*)(src + t4);
    uint2 o;
    o.x = (unsigned)f2bf(v.x) | ((unsigned)f2bf(v.y) << 16);
    o.y = (unsigned)f2bf(v.z) | ((unsigned)f2bf(v.w) << 16);
    *(uint2*)(d + t4) = o;
}

// ---------------------------------------------------------------------------
// Kernel 0b: bias -> bf16 in MFMA-fragment-permuted layout.
// P[b][nt][tt][m][col][r]  (dims 16,64,8,8,16,16; r fastest) so that the attn
// wave's per-(tt,m) bias read is ONE coalesced 8B load per lane (512 B/wave,
// each HBM byte fetched exactly once). Tiled transpose through LDS:
// coalesced float4 reads, coalesced uint4 writes.
// ---------------------------------------------------------------------------
__global__ __launch_bounds__(256) void bias_cvt_perm(
    const float* __restrict__ sp, const float* __restrict__ ed,
    unsigned short* __restrict__ P)
{
    const int nt = blockIdx.x, b = blockIdx.y;
    const int t = threadIdx.x;
    __shared__ unsigned short lds[16][1032];   // +8 pad: stride 2064B
    const size_t src0 = ((size_t)b * Nq + nt * 16) * Nq;

    for (int idx = t; idx < 4096; idx += 256) {
        const int r = idx >> 8, c4 = (idx & 255) * 4;
        float4 a = *(const float4*)(sp + src0 + (size_t)r * Nq + c4);
        float4 e = *(const float4*)(ed + src0 + (size_t)r * Nq + c4);
        uint2 o;
        o.x = (unsigned)f2bf(a.x + e.x) | ((unsigned)f2bf(a.y + e.y) << 16);
        o.y = (unsigned)f2bf(a.z + e.z) | ((unsigned)f2bf(a.w + e.w) << 16);
        *(uint2*)&lds[r][c4] = o;
    }
    __syncthreads();

    unsigned short* Ps = P + ((size_t)(b * 64 + nt) << 14);   // 16384 u16/slice
    #pragma unroll
    for (int it = 0; it < 8; it++) {
        const int o   = (it * 256 + t) * 8;
        const int r0  = o & 15;            // 0 or 8
        const int col = (o >> 4) & 15;
        const int m   = (o >> 8) & 7;
        const int tt  = (o >> 11) & 7;
        const int c   = tt * 128 + m * 16 + col;
        uint4 w;
        w.x = (unsigned)lds[r0 + 0][c] | ((unsigned)lds[r0 + 1][c] << 16);
        w.y = (unsigned)lds[r0 + 2][c] | ((unsigned)lds[r0 + 3][c] << 16);
        w.z = (unsigned)lds[r0 + 4][c] | ((unsigned)lds[r0 + 5][c] << 16);
        w.w = (unsigned)lds[r0 + 6][c] | ((unsigned)lds[r0 + 7][c] << 16);
        *(uint4*)(Ps + o) = w;
    }
}

// ---------------------------------------------------------------------------
// Kernel 1: fused double LayerNorm -> bf16 outputs (shared mean/rstd)
// ---------------------------------------------------------------------------
__global__ __launch_bounds__(256) void ln2_kernel(
    const float* __restrict__ x,
    const float* __restrict__ g1, const float* __restrict__ bb1,
    const float* __restrict__ g2, const float* __restrict__ bb2,
    unsigned short* __restrict__ att_in, unsigned short* __restrict__ ffn_in)
{
    const int row = blockIdx.x;
    const int t = threadIdx.x;
    const size_t base = (size_t)row * Dq;
    float v = x[base + t];

    float s = v, sq = v * v;
    #pragma unroll
    for (int off = 32; off > 0; off >>= 1) {
        s  += __shfl_down(s, off);
        sq += __shfl_down(sq, off);
    }
    __shared__ float ssum[4], ssq[4];
    __shared__ float mu_s, rstd_s;
    const int lane = t & 63, wid = t >> 6;
    if (lane == 0) { ssum[wid] = s; ssq[wid] = sq; }
    __syncthreads();
    if (t == 0) {
        float S = ssum[0] + ssum[1] + ssum[2] + ssum[3];
        float Q = ssq[0] + ssq[1] + ssq[2] + ssq[3];
        float mu = S * (1.0f / Dq);
        float var = Q * (1.0f / Dq) - mu * mu;
        mu_s = mu;
        rstd_s = rsqrtf(var + LN_EPS);
    }
    __syncthreads();
    const float nx = (v - mu_s) * rstd_s;
    att_in[base + t] = f2bf(nx * g1[t] + bb1[t]);
    ffn_in[base + t] = f2bf(nx * g2[t] + bb2[t]);
}

// ---------------------------------------------------------------------------
// Kernel 2: MFMA NT GEMM  C[M,Nc] = A[M,K] * W[Nc,K]^T  (bf16 in, fp32 acc)
// 128x128 tile, BK=32, operand-swapped (W = A-operand) for vector epilogue.
// mode 0: fp32 out (+bias,+gelu,+add)   [Wo, FFN2]
// mode 1: bf16 flat out (+bias,+gelu)   [FFN1]
// mode 2: merged QKV (Nc=768): Q scaled+head-major, K head-major, V transposed
// ---------------------------------------------------------------------------
#define TM 128
#define TN 128
#define TK 32

__global__ __launch_bounds__(256) void gemm_mfma(
    const unsigned short* __restrict__ A, const unsigned short* __restrict__ W,
    const float* __restrict__ bias, const float* __restrict__ add,
    float* __restrict__ outF, unsigned short* __restrict__ outBF,
    unsigned short* __restrict__ Qb, unsigned short* __restrict__ Kb,
    unsigned short* __restrict__ Vt,
    int M, int Nc, int K, int mode, int apply_gelu)
{
    __shared__ unsigned short As[TM * TK];   // 8 KB
    __shared__ unsigned short Bs[TN * TK];   // 8 KB
    const int t = threadIdx.x;
    const int w = t >> 6, lane = t & 63;
    const int col = lane & 15, quad = lane >> 4;
    const int wr = w >> 1, wc = w & 1;
    const int row0 = blockIdx.y * TM;
    const int col0 = blockIdx.x * TN;

    f32x4 acc[4][4] = {};

    for (int k0 = 0; k0 < K; k0 += TK) {
        #pragma unroll
        for (int j = 0; j < 2; j++) {
            const int c = w * 128 + j * 64 + lane;   // chunk 0..511 (16B each)
            const int r = c >> 2, seg = c & 3;
            async16(&As[(size_t)(w * 128 + j * 64) * 8],
                    A + (size_t)(row0 + r) * K + k0 + seg * 8);
            async16(&Bs[(size_t)(w * 128 + j * 64) * 8],
                    W + (size_t)(col0 + r) * K + k0 + seg * 8);
        }
        __syncthreads();   // drains vmcnt (global_load_lds) + barrier
        short8 wf[4], af[4];
        #pragma unroll
        for (int i = 0; i < 4; i++)
            wf[i] = *(const short8*)&Bs[(wc * 64 + i * 16 + col) * TK + quad * 8];
        #pragma unroll
        for (int j = 0; j < 4; j++)
            af[j] = *(const short8*)&As[(wr * 64 + j * 16 + col) * TK + quad * 8];
        // D[c][r]: A-operand = W rows (c), B-operand = A rows (r)
        #pragma unroll
        for (int i = 0; i < 4; i++)
            #pragma unroll
            for (int j = 0; j < 4; j++)
                acc[i][j] = __builtin_amdgcn_mfma_f32_16x16x32_bf16(wf[i], af[j], acc[i][j], 0, 0, 0);
        __syncthreads();
    }

    // epilogue: lane owns cols c0..c0+3 (consecutive), output row r
    #pragma unroll
    for (int i = 0; i < 4; i++) {
        #pragma unroll
        for (int j = 0; j < 4; j++) {
            const int c0 = col0 + wc * 64 + i * 16 + quad * 4;
            const int r  = row0 + wr * 64 + j * 16 + col;
            float4 v = make_float4(acc[i][j][0], acc[i][j][1], acc[i][j][2], acc[i][j][3]);
            if (mode == 2 && c0 < 256) { v.x *= SCALE; v.y *= SCALE; v.z *= SCALE; v.w *= SCALE; }
            if (bias) {
                float4 bb = *(const float4*)&bias[c0];
                v.x += bb.x; v.y += bb.y; v.z += bb.z; v.w += bb.w;
            }
            if (apply_gelu) {
                v.x = gelu_tanh(v.x); v.y = gelu_tanh(v.y);
                v.z = gelu_tanh(v.z); v.w = gelu_tanh(v.w);
            }
            if (add) {
                float4 aa = *(const float4*)&add[(size_t)r * Nc + c0];
                v.x += aa.x; v.y += aa.y; v.z += aa.z; v.w += aa.w;
            }
            if (mode == 0) {
                *(float4*)&outF[(size_t)r * Nc + c0] = v;
            } else if (mode == 1) {
                uint2 o;
                o.x = (unsigned)f2bf(v.x) | ((unsigned)f2bf(v.y) << 16);
                o.y = (unsigned)f2bf(v.z) | ((unsigned)f2bf(v.w) << 16);
                *(uint2*)&outBF[(size_t)r * Nc + c0] = o;
            } else {
                const int b = r >> 10, n = r & 1023;
                if (c0 < 512) {
                    // Q (c0<256, pre-scaled) or K: head-major [B,H,N,32]
                    const int cq = c0 & 255;
                    const int h = cq >> 5, d0 = cq & 31;
                    unsigned short* dst = (c0 < 256 ? Qb : Kb);
                    uint2 o;
                    o.x = (unsigned)f2bf(v.x) | ((unsigned)f2bf(v.y) << 16);
                    o.y = (unsigned)f2bf(v.z) | ((unsigned)f2bf(v.w) << 16);
                    *(uint2*)&dst[(((size_t)(b * Hq + h) << 10) + n) * HDq + d0] = o;
                } else {
                    // V transposed: Vt[B,H,32,N]
                    const int cv = c0 - 512;
                    const int h = cv >> 5, d0 = cv & 31;
                    unsigned short* dst = Vt + (((size_t)(b * Hq + h) * HDq + d0) << 10) + n;
                    dst[0]      = f2bf(v.x);
                    dst[1024]   = f2bf(v.y);
                    dst[2048]   = f2bf(v.z);
                    dst[3072]   = f2bf(v.w);
                }
            }
        }
    }
}

// ---------------------------------------------------------------------------
// Kernel 3: MFMA attention, wave-autonomous flash-style, ZERO barriers.
// Block = (b, 16 q-rows), 512 threads = 8 waves, wave w == head w.
// Bias comes pre-permuted (bias_cvt_perm): per (tt,m) each lane does ONE
// coalesced 8B load that lands exactly in MFMA C-fragment order -> bias HBM
// bytes fetched once, no LDS staging, no barriers. LDS = 32 KB S-tiles ->
// 4 blocks/CU (87% occupancy).
// XCD-bijective swizzle: flat -> (flat&7)*128 + flat>>3 puts batches {2k,2k+1}
// on XCD k, so each XCD's K/V working set is 2 MB < 4 MB L2 (K/V fetched from
// HBM once per XCD instead of streaming from L3 every pass).
// S-tile XOR swizzle (short idx ^= (row&7)<<3): conflict-free b128 PV reads.
// ---------------------------------------------------------------------------
__global__ __launch_bounds__(512, 8) void attn_mfma(
    const unsigned short* __restrict__ Qbf, const unsigned short* __restrict__ Kbf,
    const unsigned short* __restrict__ Vt, const unsigned short* __restrict__ biasP,
    unsigned short* __restrict__ O16)
{
    // XCD-aware bijective remap (1024 blocks % 8 == 0)
    const int flat = blockIdx.y * gridDim.x + blockIdx.x;
    const int id2  = (flat & 7) * 128 + (flat >> 3);
    const int b    = id2 >> 6;
    const int nt   = id2 & 63;
    const int n0   = nt * 16;

    const int t = threadIdx.x;
    const int h = t >> 6;            // wave index == head
    const int lane = t & 63;
    const int col = lane & 15;
    const int quad = lane >> 4;

    __shared__ unsigned short S16[8][16 * 128];    // 32 KB, 4KB per wave

    const size_t hb = (size_t)b * Hq + h;
    const unsigned short* Qh = Qbf + hb * (Nq * HDq);
    const unsigned short* Kh = Kbf + hb * (Nq * HDq);
    const unsigned short* Vh = Vt  + hb * (HDq * Nq);
    const unsigned short* Ps = biasP + ((size_t)(b * 64 + nt) << 14);
    unsigned short* Sw = &S16[h][0];

    // A-frag: Q rows n0..n0+15 (pre-scaled by 1/16 in gemm epilogue)
    const short8 aq = *(const short8*)(Qh + (size_t)(n0 + col) * HDq + quad * 8);

    f32x4 o0 = {0.f, 0.f, 0.f, 0.f}, o1 = {0.f, 0.f, 0.f, 0.f};
    float rsum[4] = {0.f, 0.f, 0.f, 0.f};

    for (int tt = 0; tt < 8; tt++) {                   // 128-key flash tiles
        const int k0 = tt * 128;
        // ---- QK^T + bias + exp -> per-wave swizzled S-tile
        #pragma unroll
        for (int m = 0; m < 8; m++) {
            const int m0 = k0 + m * 16;
            short8 bk = *(const short8*)(Kh + (size_t)(m0 + col) * HDq + quad * 8);
            uint2 bv = *(const uint2*)(Ps + ((tt * 8 + m) << 8) + col * 16 + quad * 4);
            f32x4 cc = {0.f, 0.f, 0.f, 0.f};
            cc = __builtin_amdgcn_mfma_f32_16x16x32_bf16(aq, bk, cc, 0, 0, 0);
            const float bi[4] = {
                bf2f((unsigned short)(bv.x & 0xffff)), bf2f((unsigned short)(bv.x >> 16)),
                bf2f((unsigned short)(bv.y & 0xffff)), bf2f((unsigned short)(bv.y >> 16))
            };
            #pragma unroll
            for (int i = 0; i < 4; i++) {
                const int r = quad * 4 + i;
                float s = cc[i] + bi[i];
                float e = __expf(s);
                rsum[i] += e;
                const int sidx = (r * 128 + m * 16 + col) ^ ((r & 7) << 3);
                Sw[sidx] = f2bf(e);
            }
        }
        // ---- PV: S-tile (16x128) @ V^T-rows, accumulate (same-wave LDS RAW:
        //      compiler inserts lgkmcnt waits; no barrier needed)
        #pragma unroll
        for (int c = 0; c < 4; c++) {
            const int ridx = (col * 128 + c * 32 + quad * 8) ^ ((col & 7) << 3);
            short8 ap  = *(const short8*)&Sw[ridx];
            short8 bv0 = *(const short8*)(Vh + (size_t)col * Nq + k0 + c * 32 + quad * 8);
            short8 bv1 = *(const short8*)(Vh + (size_t)(col + 16) * Nq + k0 + c * 32 + quad * 8);
            o0 = __builtin_amdgcn_mfma_f32_16x16x32_bf16(ap, bv0, o0, 0, 0, 0);
            o1 = __builtin_amdgcn_mfma_f32_16x16x32_bf16(ap, bv1, o1, 0, 0, 0);
        }
    }

    // ---- in-register row-sum reduce across the 16 col-lanes of each quad
    #pragma unroll
    for (int off = 1; off < 16; off <<= 1) {
        #pragma unroll
        for (int i = 0; i < 4; i++) rsum[i] += __shfl_xor(rsum[i], off, 16);
    }

    // ---- normalize + store: lane owns rows quad*4+i, cols col / col+16
    unsigned short* op = O16 + ((size_t)b * Nq + n0) * Dq + h * HDq;
    #pragma unroll
    for (int i = 0; i < 4; i++) {
        const float inv = 1.0f / rsum[i];
        const int q = quad * 4 + i;
        op[(size_t)q * Dq + col]      = f2bf(o0[i] * inv);
        op[(size_t)q * Dq + col + 16] = f2bf(o1[i] * inv);
    }
}

// ---------------------------------------------------------------------------
// Kernel 4: pad_mask2 — zero rows of out where att_output has any exact 0
// ---------------------------------------------------------------------------
__global__ __launch_bounds__(256) void pad2_kernel(
    const float* __restrict__ AO, float* __restrict__ out)
{
    const int row = blockIdx.x;
    const int t = threadIdx.x;
    const float v = AO[(size_t)row * Dq + t];
    unsigned long long m = __ballot(v == 0.0f);
    __shared__ unsigned long long w[4];
    if ((t & 63) == 0) w[t >> 6] = m;
    __syncthreads();
    if ((w[0] | w[1] | w[2] | w[3]) != 0ULL)
        out[(size_t)row * Dq + t] = 0.0f;
}

// ---------------------------------------------------------------------------
extern "C" void kernel_launch(void* const* d_in, const int* in_sizes, int n_in,
                              void* d_out, int out_size, void* d_ws, size_t ws_size,
                              hipStream_t stream)
{
    const float* x      = (const float*)d_in[0];
    const float* sp     = (const float*)d_in[1];
    const float* ed     = (const float*)d_in[2];
    const float* gamma1 = (const float*)d_in[3];
    const float* beta1  = (const float*)d_in[4];
    const float* gamma2 = (const float*)d_in[5];
    const float* beta2  = (const float*)d_in[6];
    const float* Wq     = (const float*)d_in[7];
    const float* Wk     = (const float*)d_in[8];
    const float* Wv     = (const float*)d_in[9];
    const float* Wo     = (const float*)d_in[10];
    const float* W1     = (const float*)d_in[11];
    const float* b1     = (const float*)d_in[12];
    const float* W2     = (const float*)d_in[13];
    const float* b2     = (const float*)d_in[14];
    float* out = (float*)d_out;

    // workspace layout (in shorts)
    unsigned short* s = (unsigned short*)d_ws;
    const size_t MD = (size_t)Mq * Dq;                  // 4.19M elements
    unsigned short* att_in16 = s;                        // [M,D] bf16; reused as O16
    unsigned short* ffn_in16 = s + MD;                   // [M,D] bf16
    unsigned short* Qbf      = s + 2 * MD;               // [B,H,N,32] bf16
    unsigned short* Kbf      = s + 3 * MD;               // [B,H,N,32] bf16
    unsigned short* Vtb      = s + 4 * MD;               // [B,H,32,N] bf16 (transposed)
    unsigned short* W16      = s + 5 * MD;               // 786432 shorts
    unsigned short* h16      = s + 5 * MD + 786432;      // [M,F] bf16 (33.5 MB)
    unsigned short* O16      = att_in16;                 // attn out (att_in dead)
    float*          AO       = (float*)Qbf;              // [M,D] fp32 (Q/K dead)
    // biasP [B][64][8][8][16][16] bf16 = 16.78M shorts == exactly h16's size;
    // biasP is dead before FFN1 writes h16 -> alias them (no extra workspace).
    unsigned short* biasP    = h16;

    unsigned short* Wo16 = W16 + 196608;
    unsigned short* W116 = W16 + 262144;
    unsigned short* W216 = W16 + 524288;

    // 0) weights -> bf16 (Wq/Wk/Wv contiguous as rows 0..767 for merged QKV)
    cvt_weights<<<768, 256, 0, stream>>>(Wq, Wk, Wv, Wo, W1, W2, W16);

    // 0b) biasP = bf16(sp + ed) in MFMA-fragment-permuted layout
    bias_cvt_perm<<<dim3(64, 16), 256, 0, stream>>>(sp, ed, biasP);

    // 1) both layernorms -> bf16
    ln2_kernel<<<Mq, 256, 0, stream>>>(x, gamma1, beta1, gamma2, beta2, att_in16, ffn_in16);

    // 2) merged QKV projection (Q scaled + head-major, K head-major, V transposed)
    dim3 gQKV(768 / TN, Mq / TM);   // (6, 128)
    gemm_mfma<<<gQKV, 256, 0, stream>>>(att_in16, W16, nullptr, nullptr, nullptr, nullptr,
                                        Qbf, Kbf, Vtb, Mq, 768, Dq, 2, 0);

    // 3) MFMA attention: block=(qt,b), 8 waves = 8 heads -> O16 (bf16 [B,N,D])
    attn_mfma<<<dim3(Nq / 16, Bq), 512, 0, stream>>>(Qbf, Kbf, Vtb, biasP, O16);

    // 4) output projection + residual: AO = O @ Wo^T + x   (fp32)
    dim3 gP(Dq / TN, Mq / TM);
    gemm_mfma<<<gP, 256, 0, stream>>>(O16, Wo16, nullptr, x, AO, nullptr,
                                      nullptr, nullptr, nullptr, Mq, Dq, Dq, 0, 0);

    // 5) FFN1: h16 = bf16(gelu(ffn_in @ W1^T + b1))
    dim3 gF1(Fq / TN, Mq / TM);
    gemm_mfma<<<gF1, 256, 0, stream>>>(ffn_in16, W116, b1, nullptr, nullptr, h16,
                                       nullptr, nullptr, nullptr, Mq, Fq, Dq, 1, 1);

    // 6) FFN2: out = h @ W2^T + b2 + AO
    gemm_mfma<<<gP, 256, 0, stream>>>(h16, W216, b2, AO, out, nullptr,
                                      nullptr, nullptr, nullptr, Mq, Dq, Fq, 0, 0);

    // 7) pad_mask2 row zeroing
    pad2_kernel<<<Mq, 256, 0, stream>>>(AO, out);
}

// Round 4
// 426.621 us; speedup vs baseline: 1.2250x; 1.1473x over previous
//
#include <hip/hip_runtime.h>
#include <hip/hip_bf16.h>
#include <math.h>

// Problem constants (B=16, N=1024, D=256, F=1024, H=8, hd=32)
#define Bq 16
#define Nq 1024
#define Dq 256
#define Fq 1024
#define Hq 8
#define HDq 32
#define Mq (Bq * Nq)          // 16384 rows
#define SCALE 0.0625f          // D^-0.5 = 1/16
#define LN_EPS 1e-5f

typedef __attribute__((ext_vector_type(8))) short short8;   // 8 bf16
typedef __attribute__((ext_vector_type(4))) float f32x4;

__device__ __forceinline__ float bf2f(unsigned short s) {
    unsigned u = ((unsigned)s) << 16;
    return __builtin_bit_cast(float, u);
}
__device__ __forceinline__ unsigned short f2bf(float f) {
    __hip_bfloat16 h = __float2bfloat16(f);
    return __builtin_bit_cast(unsigned short, h);
}

// async global->LDS, 16B per lane (lands at ldsbase + lane*16)
typedef __attribute__((address_space(3))) unsigned int lds_uint;
typedef const __attribute__((address_space(1))) unsigned int glb_uint;
__device__ __forceinline__ void async16(void* lds, const void* g) {
    __builtin_amdgcn_global_load_lds((glb_uint*)g, (lds_uint*)lds, 16, 0, 0);
}

__device__ __forceinline__ float gelu_tanh(float v) {
    const float c = 0.7978845608028654f;
    float u = c * (v + 0.044715f * v * v * v);
    return 0.5f * v * (1.0f + tanhf(u));
}

// ---------------------------------------------------------------------------
// Kernel 0: convert the 6 weight matrices to bf16 (Wq,Wk,Wv rows 0..767 of W16)
// ---------------------------------------------------------------------------
__global__ __launch_bounds__(256) void cvt_weights(
    const float* __restrict__ Wq, const float* __restrict__ Wk,
    const float* __restrict__ Wv, const float* __restrict__ Wo,
    const float* __restrict__ W1, const float* __restrict__ W2,
    unsigned short* __restrict__ dst)
{
    const int blk = blockIdx.x;
    int seg, local;
    if (blk < 256)      { seg = blk >> 6; local = blk & 63; }
    else if (blk < 512) { seg = 4; local = blk - 256; }
    else                { seg = 5; local = blk - 512; }
    const float* srcs[6] = {Wq, Wk, Wv, Wo, W1, W2};
    const size_t dsto[6] = {0, 65536, 131072, 196608, 262144, 524288};
    const float* src = srcs[seg] + (size_t)local * 1024;
    unsigned short* d = dst + dsto[seg] + (size_t)local * 1024;
    const int t4 = threadIdx.x * 4;
    float4 v = *(const float4*)(src + t4);
    uint2 o;
    o.x = (unsigned)f2bf(v.x) | ((unsigned)f2bf(v.y) << 16);
    o.y = (unsigned)f2bf(v.z) | ((unsigned)f2bf(v.w) << 16);
    *(uint2*)(d + t4) = o;
}

// ---------------------------------------------------------------------------
// Kernel 0b: bias -> bf16 in MFMA-fragment-permuted layout.
// P[b][nt][tt][m][col][r]  (dims 16,64,8,8,16,16; r fastest) so that the attn
// wave's per-(tt,m) bias read is ONE coalesced 8B load per lane (512 B/wave,
// each HBM byte fetched exactly once). Tiled transpose through LDS.
// ---------------------------------------------------------------------------
__global__ __launch_bounds__(256) void bias_cvt_perm(
    const float* __restrict__ sp, const float* __restrict__ ed,
    unsigned short* __restrict__ P)
{
    const int nt = blockIdx.x, b = blockIdx.y;
    const int t = threadIdx.x;
    __shared__ unsigned short lds[16][1032];   // +8 pad: stride 2064B
    const size_t src0 = ((size_t)b * Nq + nt * 16) * Nq;

    for (int idx = t; idx < 4096; idx += 256) {
        const int r = idx >> 8, c4 = (idx & 255) * 4;
        float4 a = *(const float4*)(sp + src0 + (size_t)r * Nq + c4);
        float4 e = *(const float4*)(ed + src0 + (size_t)r * Nq + c4);
        uint2 o;
        o.x = (unsigned)f2bf(a.x + e.x) | ((unsigned)f2bf(a.y + e.y) << 16);
        o.y = (unsigned)f2bf(a.z + e.z) | ((unsigned)f2bf(a.w + e.w) << 16);
        *(uint2*)&lds[r][c4] = o;
    }
    __syncthreads();

    unsigned short* Ps = P + ((size_t)(b * 64 + nt) << 14);   // 16384 u16/slice
    #pragma unroll
    for (int it = 0; it < 8; it++) {
        const int o   = (it * 256 + t) * 8;
        const int r0  = o & 15;            // 0 or 8
        const int col = (o >> 4) & 15;
        const int m   = (o >> 8) & 7;
        const int tt  = (o >> 11) & 7;
        const int c   = tt * 128 + m * 16 + col;
        uint4 w;
        w.x = (unsigned)lds[r0 + 0][c] | ((unsigned)lds[r0 + 1][c] << 16);
        w.y = (unsigned)lds[r0 + 2][c] | ((unsigned)lds[r0 + 3][c] << 16);
        w.z = (unsigned)lds[r0 + 4][c] | ((unsigned)lds[r0 + 5][c] << 16);
        w.w = (unsigned)lds[r0 + 6][c] | ((unsigned)lds[r0 + 7][c] << 16);
        *(uint4*)(Ps + o) = w;
    }
}

// ---------------------------------------------------------------------------
// Kernel 1: fused double LayerNorm -> bf16 outputs (shared mean/rstd)
// ---------------------------------------------------------------------------
__global__ __launch_bounds__(256) void ln2_kernel(
    const float* __restrict__ x,
    const float* __restrict__ g1, const float* __restrict__ bb1,
    const float* __restrict__ g2, const float* __restrict__ bb2,
    unsigned short* __restrict__ att_in, unsigned short* __restrict__ ffn_in)
{
    const int row = blockIdx.x;
    const int t = threadIdx.x;
    const size_t base = (size_t)row * Dq;
    float v = x[base + t];

    float s = v, sq = v * v;
    #pragma unroll
    for (int off = 32; off > 0; off >>= 1) {
        s  += __shfl_down(s, off);
        sq += __shfl_down(sq, off);
    }
    __shared__ float ssum[4], ssq[4];
    __shared__ float mu_s, rstd_s;
    const int lane = t & 63, wid = t >> 6;
    if (lane == 0) { ssum[wid] = s; ssq[wid] = sq; }
    __syncthreads();
    if (t == 0) {
        float S = ssum[0] + ssum[1] + ssum[2] + ssum[3];
        float Q = ssq[0] + ssq[1] + ssq[2] + ssq[3];
        float mu = S * (1.0f / Dq);
        float var = Q * (1.0f / Dq) - mu * mu;
        mu_s = mu;
        rstd_s = rsqrtf(var + LN_EPS);
    }
    __syncthreads();
    const float nx = (v - mu_s) * rstd_s;
    att_in[base + t] = f2bf(nx * g1[t] + bb1[t]);
    ffn_in[base + t] = f2bf(nx * g2[t] + bb2[t]);
}

// ---------------------------------------------------------------------------
// Kernel 2: MFMA NT GEMM  C[M,Nc] = A[M,K] * W[Nc,K]^T  (bf16 in, fp32 acc)
// 128x128 tile, BK=32, operand-swapped (W = A-operand) for vector epilogue.
// mode 0: fp32 out (+bias,+gelu,+add)   [Wo, FFN2]
// mode 1: bf16 flat out (+bias,+gelu)   [FFN1]
// mode 2: merged QKV (Nc=768): Q scaled+head-major, K head-major, V transposed
// ---------------------------------------------------------------------------
#define TM 128
#define TN 128
#define TK 32

__global__ __launch_bounds__(256) void gemm_mfma(
    const unsigned short* __restrict__ A, const unsigned short* __restrict__ W,
    const float* __restrict__ bias, const float* __restrict__ add,
    float* __restrict__ outF, unsigned short* __restrict__ outBF,
    unsigned short* __restrict__ Qb, unsigned short* __restrict__ Kb,
    unsigned short* __restrict__ Vt,
    int M, int Nc, int K, int mode, int apply_gelu)
{
    __shared__ unsigned short As[TM * TK];   // 8 KB
    __shared__ unsigned short Bs[TN * TK];   // 8 KB
    const int t = threadIdx.x;
    const int w = t >> 6, lane = t & 63;
    const int col = lane & 15, quad = lane >> 4;
    const int wr = w >> 1, wc = w & 1;
    const int row0 = blockIdx.y * TM;
    const int col0 = blockIdx.x * TN;

    f32x4 acc[4][4] = {};

    for (int k0 = 0; k0 < K; k0 += TK) {
        #pragma unroll
        for (int j = 0; j < 2; j++) {
            const int c = w * 128 + j * 64 + lane;   // chunk 0..511 (16B each)
            const int r = c >> 2, seg = c & 3;
            async16(&As[(size_t)(w * 128 + j * 64) * 8],
                    A + (size_t)(row0 + r) * K + k0 + seg * 8);
            async16(&Bs[(size_t)(w * 128 + j * 64) * 8],
                    W + (size_t)(col0 + r) * K + k0 + seg * 8);
        }
        __syncthreads();   // drains vmcnt (global_load_lds) + barrier
        short8 wf[4], af[4];
        #pragma unroll
        for (int i = 0; i < 4; i++)
            wf[i] = *(const short8*)&Bs[(wc * 64 + i * 16 + col) * TK + quad * 8];
        #pragma unroll
        for (int j = 0; j < 4; j++)
            af[j] = *(const short8*)&As[(wr * 64 + j * 16 + col) * TK + quad * 8];
        // D[c][r]: A-operand = W rows (c), B-operand = A rows (r)
        #pragma unroll
        for (int i = 0; i < 4; i++)
            #pragma unroll
            for (int j = 0; j < 4; j++)
                acc[i][j] = __builtin_amdgcn_mfma_f32_16x16x32_bf16(wf[i], af[j], acc[i][j], 0, 0, 0);
        __syncthreads();
    }

    // epilogue: lane owns cols c0..c0+3 (consecutive), output row r
    #pragma unroll
    for (int i = 0; i < 4; i++) {
        #pragma unroll
        for (int j = 0; j < 4; j++) {
            const int c0 = col0 + wc * 64 + i * 16 + quad * 4;
            const int r  = row0 + wr * 64 + j * 16 + col;
            float4 v = make_float4(acc[i][j][0], acc[i][j][1], acc[i][j][2], acc[i][j][3]);
            if (mode == 2 && c0 < 256) { v.x *= SCALE; v.y *= SCALE; v.z *= SCALE; v.w *= SCALE; }
            if (bias) {
                float4 bb = *(const float4*)&bias[c0];
                v.x += bb.x; v.y += bb.y; v.z += bb.z; v.w += bb.w;
            }
            if (apply_gelu) {
                v.x = gelu_tanh(v.x); v.y = gelu_tanh(v.y);
                v.z = gelu_tanh(v.z); v.w = gelu_tanh(v.w);
            }
            if (add) {
                float4 aa = *(const float4*)&add[(size_t)r * Nc + c0];
                v.x += aa.x; v.y += aa.y; v.z += aa.z; v.w += aa.w;
            }
            if (mode == 0) {
                *(float4*)&outF[(size_t)r * Nc + c0] = v;
            } else if (mode == 1) {
                uint2 o;
                o.x = (unsigned)f2bf(v.x) | ((unsigned)f2bf(v.y) << 16);
                o.y = (unsigned)f2bf(v.z) | ((unsigned)f2bf(v.w) << 16);
                *(uint2*)&outBF[(size_t)r * Nc + c0] = o;
            } else {
                const int b = r >> 10, n = r & 1023;
                if (c0 < 512) {
                    // Q (c0<256, pre-scaled) or K: head-major [B,H,N,32]
                    const int cq = c0 & 255;
                    const int h = cq >> 5, d0 = cq & 31;
                    unsigned short* dst = (c0 < 256 ? Qb : Kb);
                    uint2 o;
                    o.x = (unsigned)f2bf(v.x) | ((unsigned)f2bf(v.y) << 16);
                    o.y = (unsigned)f2bf(v.z) | ((unsigned)f2bf(v.w) << 16);
                    *(uint2*)&dst[(((size_t)(b * Hq + h) << 10) + n) * HDq + d0] = o;
                } else {
                    // V transposed: Vt[B,H,32,N]
                    const int cv = c0 - 512;
                    const int h = cv >> 5, d0 = cv & 31;
                    unsigned short* dst = Vt + (((size_t)(b * Hq + h) * HDq + d0) << 10) + n;
                    dst[0]      = f2bf(v.x);
                    dst[1024]   = f2bf(v.y);
                    dst[2048]   = f2bf(v.z);
                    dst[3072]   = f2bf(v.w);
                }
            }
        }
    }
}

// ---------------------------------------------------------------------------
// Kernel 3: MFMA attention with K/V fully LDS-resident.
// Block = (b, h, n-half): 256 blocks (1/CU), 512 thr = 8 waves; K (64KB) and
// V (64KB) for this head staged ONCE via global_load_lds -> K/V HBM traffic
// is exactly 2x their size (33.6 MB total), replacing round-3's ~200 MB of
// L2/L3-miss refetch. Per wave: 4 q-tiles of 16 rows; K/V fragments hoisted
// per-tt and reused across the 4 q-tiles (4x fewer LDS frag reads).
// Swizzles (all XOR-involutions, staged via pre-swizzled GLOBAL source since
// global_load_lds writes linearly):
//   K u16 idx ^= ((idx>>... row>>1)&3)<<3  -> frag reads 2-way conflict (free)
//   V u16 idx ^= (row&7)<<3                -> frag reads 2-way conflict (free)
//   S u16 idx ^= (row&7)<<3                -> b128 PV reads conflict-free
// Bias read directly from permuted biasP (coalesced uint2/lane, bytes once).
// XCD map: id2=(flat&7)*32+flat>>3 puts b in {2k,2k+1} on XCD k (bias + K/V
// L2 locality). One barrier total (post-staging).
// ---------------------------------------------------------------------------
__global__ __launch_bounds__(512, 2) void attn_mfma(
    const unsigned short* __restrict__ Qbf, const unsigned short* __restrict__ Kbf,
    const unsigned short* __restrict__ Vt, const unsigned short* __restrict__ biasP,
    unsigned short* __restrict__ O16)
{
    const int flat = blockIdx.x;
    const int id2  = (flat & 7) * 32 + (flat >> 3);   // bijective, 256 % 8 == 0
    const int b    = id2 >> 4;
    const int h    = (id2 >> 1) & 7;
    const int nh   = id2 & 1;

    const int t = threadIdx.x;
    const int w = t >> 6;
    const int lane = t & 63;
    const int col = lane & 15;
    const int quad = lane >> 4;

    __shared__ unsigned short Klds[32768];     // 64 KB  [1024][32] swizzled
    __shared__ unsigned short Vlds[32768];     // 64 KB  [32][1024] swizzled
    __shared__ unsigned short S16[8][2048];    // 32 KB, 4 KB per wave

    const size_t hb = (size_t)b * Hq + h;
    const unsigned short* Qh = Qbf + hb * (Nq * HDq);
    const unsigned short* Kh = Kbf + hb * (Nq * HDq);
    const unsigned short* Vh = Vt  + hb * (HDq * Nq);

    // ---- stage K,V -> LDS (linear dest, inverse-swizzled source)
    #pragma unroll
    for (int i = 0; i < 8; i++) {
        const int ck = i * 512 + t;                    // 16B chunk id, 0..4095
        async16(&Klds[ck * 8], Kh + ((ck * 8) ^ (((ck >> 3) & 3) << 3)));
        async16(&Vlds[ck * 8], Vh + ((ck * 8) ^ (((ck >> 7) & 7) << 3)));
    }

    // ---- Q rows for my 4 q-tiles (independent of staging)
    const int n0 = nh * 512 + w * 64;
    short8 aq[4];
    #pragma unroll
    for (int qt = 0; qt < 4; qt++)
        aq[qt] = *(const short8*)(Qh + (size_t)(n0 + qt * 16 + col) * HDq + quad * 8);

    const unsigned short* Ps0 = biasP + ((size_t)(b * 64 + nh * 32 + w * 4) << 14);
    unsigned short* Sw = &S16[w][0];

    __syncthreads();   // staging complete — the only barrier

    f32x4 o0[4] = {{0.f,0.f,0.f,0.f},{0.f,0.f,0.f,0.f},{0.f,0.f,0.f,0.f},{0.f,0.f,0.f,0.f}};
    f32x4 o1[4] = {{0.f,0.f,0.f,0.f},{0.f,0.f,0.f,0.f},{0.f,0.f,0.f,0.f},{0.f,0.f,0.f,0.f}};
    float rsum[4][4] = {};

    for (int tt = 0; tt < 8; tt++) {                   // 128-key tiles
        const int k0 = tt * 128;
        // K/V fragments for this tile: shared by all 4 q-tiles
        short8 kf[8], vf0[4], vf1[4];
        #pragma unroll
        for (int m = 0; m < 8; m++)
            kf[m] = *(const short8*)&Klds[((k0 + m * 16 + col) * 32 + quad * 8)
                                          ^ (((col >> 1) & 3) << 3)];
        #pragma unroll
        for (int c = 0; c < 4; c++) {
            vf0[c] = *(const short8*)&Vlds[((col << 10) + k0 + c * 32 + quad * 8)
                                           ^ ((col & 7) << 3)];
            vf1[c] = *(const short8*)&Vlds[(((col + 16) << 10) + k0 + c * 32 + quad * 8)
                                           ^ ((col & 7) << 3)];
        }
        #pragma unroll
        for (int qt = 0; qt < 4; qt++) {
            const unsigned short* Psq = Ps0 + (qt << 14) + (tt << 11);
            // ---- QK^T + bias + exp -> per-wave swizzled S-tile
            #pragma unroll
            for (int m = 0; m < 8; m++) {
                f32x4 cc = {0.f, 0.f, 0.f, 0.f};
                cc = __builtin_amdgcn_mfma_f32_16x16x32_bf16(aq[qt], kf[m], cc, 0, 0, 0);
                uint2 bv = *(const uint2*)(Psq + (m << 8) + col * 16 + quad * 4);
                const float bi[4] = {
                    bf2f((unsigned short)(bv.x & 0xffff)), bf2f((unsigned short)(bv.x >> 16)),
                    bf2f((unsigned short)(bv.y & 0xffff)), bf2f((unsigned short)(bv.y >> 16))
                };
                #pragma unroll
                for (int i = 0; i < 4; i++) {
                    const int r = quad * 4 + i;
                    float e = __expf(cc[i] + bi[i]);
                    rsum[qt][i] += e;
                    const int sidx = (r * 128 + m * 16 + col) ^ ((r & 7) << 3);
                    Sw[sidx] = f2bf(e);
                }
            }
            // ---- PV: S-tile @ V (same-wave LDS RAW; compiler inserts waits)
            #pragma unroll
            for (int c = 0; c < 4; c++) {
                const int ridx = (col * 128 + c * 32 + quad * 8) ^ ((col & 7) << 3);
                short8 ap = *(const short8*)&Sw[ridx];
                o0[qt] = __builtin_amdgcn_mfma_f32_16x16x32_bf16(ap, vf0[c], o0[qt], 0, 0, 0);
                o1[qt] = __builtin_amdgcn_mfma_f32_16x16x32_bf16(ap, vf1[c], o1[qt], 0, 0, 0);
            }
        }
    }

    // ---- row-sum reduce (16 col-lanes per quad) + normalize + store
    #pragma unroll
    for (int qt = 0; qt < 4; qt++) {
        #pragma unroll
        for (int off = 1; off < 16; off <<= 1) {
            #pragma unroll
            for (int i = 0; i < 4; i++) rsum[qt][i] += __shfl_xor(rsum[qt][i], off, 16);
        }
        unsigned short* op = O16 + ((size_t)b * Nq + n0 + qt * 16) * Dq + h * HDq;
        #pragma unroll
        for (int i = 0; i < 4; i++) {
            const float inv = 1.0f / rsum[qt][i];
            const int q = quad * 4 + i;
            op[(size_t)q * Dq + col]      = f2bf(o0[qt][i] * inv);
            op[(size_t)q * Dq + col + 16] = f2bf(o1[qt][i] * inv);
        }
    }
}

// ---------------------------------------------------------------------------
// Kernel 4: pad_mask2 — zero rows of out where att_output has any exact 0
// ---------------------------------------------------------------------------
__global__ __launch_bounds__(256) void pad2_kernel(
    const float* __restrict__ AO, float* __restrict__ out)
{
    const int row = blockIdx.x;
    const int t = threadIdx.x;
    const float v = AO[(size_t)row * Dq + t];
    unsigned long long m = __ballot(v == 0.0f);
    __shared__ unsigned long long w[4];
    if ((t & 63) == 0) w[t >> 6] = m;
    __syncthreads();
    if ((w[0] | w[1] | w[2] | w[3]) != 0ULL)
        out[(size_t)row * Dq + t] = 0.0f;
}

// ---------------------------------------------------------------------------
extern "C" void kernel_launch(void* const* d_in, const int* in_sizes, int n_in,
                              void* d_out, int out_size, void* d_ws, size_t ws_size,
                              hipStream_t stream)
{
    const float* x      = (const float*)d_in[0];
    const float* sp     = (const float*)d_in[1];
    const float* ed     = (const float*)d_in[2];
    const float* gamma1 = (const float*)d_in[3];
    const float* beta1  = (const float*)d_in[4];
    const float* gamma2 = (const float*)d_in[5];
    const float* beta2  = (const float*)d_in[6];
    const float* Wq     = (const float*)d_in[7];
    const float* Wk     = (const float*)d_in[8];
    const float* Wv     = (const float*)d_in[9];
    const float* Wo     = (const float*)d_in[10];
    const float* W1     = (const float*)d_in[11];
    const float* b1     = (const float*)d_in[12];
    const float* W2     = (const float*)d_in[13];
    const float* b2     = (const float*)d_in[14];
    float* out = (float*)d_out;

    // workspace layout (in shorts)
    unsigned short* s = (unsigned short*)d_ws;
    const size_t MD = (size_t)Mq * Dq;                  // 4.19M elements
    unsigned short* att_in16 = s;                        // [M,D] bf16; reused as O16
    unsigned short* ffn_in16 = s + MD;                   // [M,D] bf16
    unsigned short* Qbf      = s + 2 * MD;               // [B,H,N,32] bf16
    unsigned short* Kbf      = s + 3 * MD;               // [B,H,N,32] bf16
    unsigned short* Vtb      = s + 4 * MD;               // [B,H,32,N] bf16 (transposed)
    unsigned short* W16      = s + 5 * MD;               // 786432 shorts
    unsigned short* h16      = s + 5 * MD + 786432;      // [M,F] bf16 (33.5 MB)
    unsigned short* O16      = att_in16;                 // attn out (att_in dead)
    float*          AO       = (float*)Qbf;              // [M,D] fp32 (Q/K dead)
    // biasP [B][64][8][8][16][16] bf16 = 16.78M shorts == exactly h16's size;
    // biasP is dead before FFN1 writes h16 -> alias them (no extra workspace).
    unsigned short* biasP    = h16;

    unsigned short* Wo16 = W16 + 196608;
    unsigned short* W116 = W16 + 262144;
    unsigned short* W216 = W16 + 524288;

    // 0) weights -> bf16 (Wq/Wk/Wv contiguous as rows 0..767 for merged QKV)
    cvt_weights<<<768, 256, 0, stream>>>(Wq, Wk, Wv, Wo, W1, W2, W16);

    // 0b) biasP = bf16(sp + ed) in MFMA-fragment-permuted layout
    bias_cvt_perm<<<dim3(64, 16), 256, 0, stream>>>(sp, ed, biasP);

    // 1) both layernorms -> bf16
    ln2_kernel<<<Mq, 256, 0, stream>>>(x, gamma1, beta1, gamma2, beta2, att_in16, ffn_in16);

    // 2) merged QKV projection (Q scaled + head-major, K head-major, V transposed)
    dim3 gQKV(768 / TN, Mq / TM);   // (6, 128)
    gemm_mfma<<<gQKV, 256, 0, stream>>>(att_in16, W16, nullptr, nullptr, nullptr, nullptr,
                                        Qbf, Kbf, Vtb, Mq, 768, Dq, 2, 0);

    // 3) attention: 256 blocks = (b, h, n-half), K/V LDS-resident
    attn_mfma<<<256, 512, 0, stream>>>(Qbf, Kbf, Vtb, biasP, O16);

    // 4) output projection + residual: AO = O @ Wo^T + x   (fp32)
    dim3 gP(Dq / TN, Mq / TM);
    gemm_mfma<<<gP, 256, 0, stream>>>(O16, Wo16, nullptr, x, AO, nullptr,
                                      nullptr, nullptr, nullptr, Mq, Dq, Dq, 0, 0);

    // 5) FFN1: h16 = bf16(gelu(ffn_in @ W1^T + b1))
    dim3 gF1(Fq / TN, Mq / TM);
    gemm_mfma<<<gF1, 256, 0, stream>>>(ffn_in16, W116, b1, nullptr, nullptr, h16,
                                       nullptr, nullptr, nullptr, Mq, Fq, Dq, 1, 1);

    // 6) FFN2: out = h @ W2^T + b2 + AO
    gemm_mfma<<<gP, 256, 0, stream>>>(h16, W216, b2, AO, out, nullptr,
                                      nullptr, nullptr, nullptr, Mq, Dq, Fq, 0, 0);

    // 7) pad_mask2 row zeroing
    pad2_kernel<<<Mq, 256, 0, stream>>>(AO, out);
}

// Round 5
// 385.799 us; speedup vs baseline: 1.3546x; 1.1058x over previous
//
#include <hip/hip_runtime.h>
#include <hip/hip_bf16.h>
#include <math.h>

// Problem constants (B=16, N=1024, D=256, F=1024, H=8, hd=32)
#define Bq 16
#define Nq 1024
#define Dq 256
#define Fq 1024
#define Hq 8
#define HDq 32
#define Mq (Bq * Nq)          // 16384 rows
#define SCALE 0.0625f          // D^-0.5 = 1/16
#define LN_EPS 1e-5f

typedef __attribute__((ext_vector_type(8))) short short8;   // 8 bf16
typedef __attribute__((ext_vector_type(4))) float f32x4;

__device__ __forceinline__ float bf2f(unsigned short s) {
    unsigned u = ((unsigned)s) << 16;
    return __builtin_bit_cast(float, u);
}
__device__ __forceinline__ unsigned short f2bf(float f) {
    __hip_bfloat16 h = __float2bfloat16(f);
    return __builtin_bit_cast(unsigned short, h);
}

// async global->LDS, 16B per lane (lands at ldsbase + lane*16)
typedef __attribute__((address_space(3))) unsigned int lds_uint;
typedef const __attribute__((address_space(1))) unsigned int glb_uint;
__device__ __forceinline__ void async16(void* lds, const void* g) {
    __builtin_amdgcn_global_load_lds((glb_uint*)g, (lds_uint*)lds, 16, 0, 0);
}

__device__ __forceinline__ float gelu_tanh(float v) {
    const float c = 0.7978845608028654f;
    float u = c * (v + 0.044715f * v * v * v);
    return 0.5f * v * (1.0f + tanhf(u));
}

// ---------------------------------------------------------------------------
// Kernel 0: convert the 6 weight matrices to bf16 (Wq,Wk,Wv rows 0..767 of W16)
// ---------------------------------------------------------------------------
__global__ __launch_bounds__(256) void cvt_weights(
    const float* __restrict__ Wq, const float* __restrict__ Wk,
    const float* __restrict__ Wv, const float* __restrict__ Wo,
    const float* __restrict__ W1, const float* __restrict__ W2,
    unsigned short* __restrict__ dst)
{
    const int blk = blockIdx.x;
    int seg, local;
    if (blk < 256)      { seg = blk >> 6; local = blk & 63; }
    else if (blk < 512) { seg = 4; local = blk - 256; }
    else                { seg = 5; local = blk - 512; }
    const float* srcs[6] = {Wq, Wk, Wv, Wo, W1, W2};
    const size_t dsto[6] = {0, 65536, 131072, 196608, 262144, 524288};
    const float* src = srcs[seg] + (size_t)local * 1024;
    unsigned short* d = dst + dsto[seg] + (size_t)local * 1024;
    const int t4 = threadIdx.x * 4;
    float4 v = *(const float4*)(src + t4);
    uint2 o;
    o.x = (unsigned)f2bf(v.x) | ((unsigned)f2bf(v.y) << 16);
    o.y = (unsigned)f2bf(v.z) | ((unsigned)f2bf(v.w) << 16);
    *(uint2*)(d + t4) = o;
}

// ---------------------------------------------------------------------------
// Kernel 0b: bias -> bf16 in MFMA-fragment-permuted layout.
// P[b][nt][mq][col][r]  (dims 16,64,64,16,16; r fastest), mq = key-block 0..63
// so the attn wave's per-key-block bias read is ONE coalesced 8B load/lane.
// ---------------------------------------------------------------------------
__global__ __launch_bounds__(256) void bias_cvt_perm(
    const float* __restrict__ sp, const float* __restrict__ ed,
    unsigned short* __restrict__ P)
{
    const int nt = blockIdx.x, b = blockIdx.y;
    const int t = threadIdx.x;
    __shared__ unsigned short lds[16][1032];   // +8 pad: stride 2064B
    const size_t src0 = ((size_t)b * Nq + nt * 16) * Nq;

    for (int idx = t; idx < 4096; idx += 256) {
        const int r = idx >> 8, c4 = (idx & 255) * 4;
        float4 a = *(const float4*)(sp + src0 + (size_t)r * Nq + c4);
        float4 e = *(const float4*)(ed + src0 + (size_t)r * Nq + c4);
        uint2 o;
        o.x = (unsigned)f2bf(a.x + e.x) | ((unsigned)f2bf(a.y + e.y) << 16);
        o.y = (unsigned)f2bf(a.z + e.z) | ((unsigned)f2bf(a.w + e.w) << 16);
        *(uint2*)&lds[r][c4] = o;
    }
    __syncthreads();

    unsigned short* Ps = P + ((size_t)(b * 64 + nt) << 14);   // 16384 u16/slice
    #pragma unroll
    for (int it = 0; it < 8; it++) {
        const int o   = (it * 256 + t) * 8;
        const int r0  = o & 15;            // 0 or 8
        const int col = (o >> 4) & 15;
        const int mq  = (o >> 8) & 63;     // key-block 0..63
        const int c   = mq * 16 + col;
        uint4 w;
        w.x = (unsigned)lds[r0 + 0][c] | ((unsigned)lds[r0 + 1][c] << 16);
        w.y = (unsigned)lds[r0 + 2][c] | ((unsigned)lds[r0 + 3][c] << 16);
        w.z = (unsigned)lds[r0 + 4][c] | ((unsigned)lds[r0 + 5][c] << 16);
        w.w = (unsigned)lds[r0 + 6][c] | ((unsigned)lds[r0 + 7][c] << 16);
        *(uint4*)(Ps + o) = w;
    }
}

// ---------------------------------------------------------------------------
// Kernel 1: fused double LayerNorm -> bf16 outputs (shared mean/rstd)
// ---------------------------------------------------------------------------
__global__ __launch_bounds__(256) void ln2_kernel(
    const float* __restrict__ x,
    const float* __restrict__ g1, const float* __restrict__ bb1,
    const float* __restrict__ g2, const float* __restrict__ bb2,
    unsigned short* __restrict__ att_in, unsigned short* __restrict__ ffn_in)
{
    const int row = blockIdx.x;
    const int t = threadIdx.x;
    const size_t base = (size_t)row * Dq;
    float v = x[base + t];

    float s = v, sq = v * v;
    #pragma unroll
    for (int off = 32; off > 0; off >>= 1) {
        s  += __shfl_down(s, off);
        sq += __shfl_down(sq, off);
    }
    __shared__ float ssum[4], ssq[4];
    __shared__ float mu_s, rstd_s;
    const int lane = t & 63, wid = t >> 6;
    if (lane == 0) { ssum[wid] = s; ssq[wid] = sq; }
    __syncthreads();
    if (t == 0) {
        float S = ssum[0] + ssum[1] + ssum[2] + ssum[3];
        float Q = ssq[0] + ssq[1] + ssq[2] + ssq[3];
        float mu = S * (1.0f / Dq);
        float var = Q * (1.0f / Dq) - mu * mu;
        mu_s = mu;
        rstd_s = rsqrtf(var + LN_EPS);
    }
    __syncthreads();
    const float nx = (v - mu_s) * rstd_s;
    att_in[base + t] = f2bf(nx * g1[t] + bb1[t]);
    ffn_in[base + t] = f2bf(nx * g2[t] + bb2[t]);
}

// ---------------------------------------------------------------------------
// Kernel 2: MFMA NT GEMM  C[M,Nc] = A[M,K] * W[Nc,K]^T  (bf16 in, fp32 acc)
// 128x128 tile, BK=32, DOUBLE-BUFFERED prefetch (T3 minimum 2-phase): next
// K-step's global_load_lds issues into buf^1 BEFORE computing buf, so HBM/L2
// load latency hides under MFMA + frag reads; one barrier per K-step (was 2).
// mode 0: fp32 out (+bias,+gelu,+add)   [Wo, FFN2]
// mode 1: bf16 flat out (+bias,+gelu)   [FFN1]
// mode 2: merged QKV (Nc=768): Q scaled+head-major, K head-major, V transposed
// ---------------------------------------------------------------------------
#define TM 128
#define TN 128
#define TK 32

__global__ __launch_bounds__(256) void gemm_mfma(
    const unsigned short* __restrict__ A, const unsigned short* __restrict__ W,
    const float* __restrict__ bias, const float* __restrict__ add,
    float* __restrict__ outF, unsigned short* __restrict__ outBF,
    unsigned short* __restrict__ Qb, unsigned short* __restrict__ Kb,
    unsigned short* __restrict__ Vt,
    int M, int Nc, int K, int mode, int apply_gelu)
{
    __shared__ unsigned short As[2][TM * TK];   // 2 x 8 KB
    __shared__ unsigned short Bs[2][TN * TK];   // 2 x 8 KB
    const int t = threadIdx.x;
    const int w = t >> 6, lane = t & 63;
    const int col = lane & 15, quad = lane >> 4;
    const int wr = w >> 1, wc = w & 1;
    const int row0 = blockIdx.y * TM;
    const int col0 = blockIdx.x * TN;

    f32x4 acc[4][4] = {};

    // per-thread staging geometry (wave-uniform LDS base; lane scatters x16B)
    const int c0s = w * 128 + lane;          // chunk for j=0
    const int c1s = c0s + 64;                // chunk for j=1
    const int r0s = c0s >> 2, s0s = (c0s & 3) * 8;
    const int r1s = c1s >> 2, s1s = (c1s & 3) * 8;

#define STAGE(buf, kk)                                                        \
    do {                                                                      \
        async16(&As[buf][(w * 128) * 8],      A + (size_t)(row0 + r0s) * K + (kk) + s0s); \
        async16(&Bs[buf][(w * 128) * 8],      W + (size_t)(col0 + r0s) * K + (kk) + s0s); \
        async16(&As[buf][(w * 128 + 64) * 8], A + (size_t)(row0 + r1s) * K + (kk) + s1s); \
        async16(&Bs[buf][(w * 128 + 64) * 8], W + (size_t)(col0 + r1s) * K + (kk) + s1s); \
    } while (0)

    STAGE(0, 0);
    __syncthreads();   // buf0 staged

    int cur = 0;
    for (int k0 = 0; k0 < K; k0 += TK) {
        if (k0 + TK < K) STAGE(cur ^ 1, k0 + TK);   // prefetch next (async)
        short8 wf[4], af[4];
        #pragma unroll
        for (int i = 0; i < 4; i++)
            wf[i] = *(const short8*)&Bs[cur][(wc * 64 + i * 16 + col) * TK + quad * 8];
        #pragma unroll
        for (int j = 0; j < 4; j++)
            af[j] = *(const short8*)&As[cur][(wr * 64 + j * 16 + col) * TK + quad * 8];
        // D[c][r]: A-operand = W rows (c), B-operand = A rows (r)
        #pragma unroll
        for (int i = 0; i < 4; i++)
            #pragma unroll
            for (int j = 0; j < 4; j++)
                acc[i][j] = __builtin_amdgcn_mfma_f32_16x16x32_bf16(wf[i], af[j], acc[i][j], 0, 0, 0);
        __syncthreads();   // drains prefetch (vmcnt) + frag reads; swap safe
        cur ^= 1;
    }
#undef STAGE

    // epilogue: lane owns cols c0..c0+3 (consecutive), output row r
    #pragma unroll
    for (int i = 0; i < 4; i++) {
        #pragma unroll
        for (int j = 0; j < 4; j++) {
            const int c0 = col0 + wc * 64 + i * 16 + quad * 4;
            const int r  = row0 + wr * 64 + j * 16 + col;
            float4 v = make_float4(acc[i][j][0], acc[i][j][1], acc[i][j][2], acc[i][j][3]);
            if (mode == 2 && c0 < 256) { v.x *= SCALE; v.y *= SCALE; v.z *= SCALE; v.w *= SCALE; }
            if (bias) {
                float4 bb = *(const float4*)&bias[c0];
                v.x += bb.x; v.y += bb.y; v.z += bb.z; v.w += bb.w;
            }
            if (apply_gelu) {
                v.x = gelu_tanh(v.x); v.y = gelu_tanh(v.y);
                v.z = gelu_tanh(v.z); v.w = gelu_tanh(v.w);
            }
            if (add) {
                float4 aa = *(const float4*)&add[(size_t)r * Nc + c0];
                v.x += aa.x; v.y += aa.y; v.z += aa.z; v.w += aa.w;
            }
            if (mode == 0) {
                *(float4*)&outF[(size_t)r * Nc + c0] = v;
            } else if (mode == 1) {
                uint2 o;
                o.x = (unsigned)f2bf(v.x) | ((unsigned)f2bf(v.y) << 16);
                o.y = (unsigned)f2bf(v.z) | ((unsigned)f2bf(v.w) << 16);
                *(uint2*)&outBF[(size_t)r * Nc + c0] = o;
            } else {
                const int b = r >> 10, n = r & 1023;
                if (c0 < 512) {
                    // Q (c0<256, pre-scaled) or K: head-major [B,H,N,32]
                    const int cq = c0 & 255;
                    const int h = cq >> 5, d0 = cq & 31;
                    unsigned short* dst = (c0 < 256 ? Qb : Kb);
                    uint2 o;
                    o.x = (unsigned)f2bf(v.x) | ((unsigned)f2bf(v.y) << 16);
                    o.y = (unsigned)f2bf(v.z) | ((unsigned)f2bf(v.w) << 16);
                    *(uint2*)&dst[(((size_t)(b * Hq + h) << 10) + n) * HDq + d0] = o;
                } else {
                    // V transposed: Vt[B,H,32,N]
                    const int cv = c0 - 512;
                    const int h = cv >> 5, d0 = cv & 31;
                    unsigned short* dst = Vt + (((size_t)(b * Hq + h) * HDq + d0) << 10) + n;
                    dst[0]      = f2bf(v.x);
                    dst[1024]   = f2bf(v.y);
                    dst[2048]   = f2bf(v.z);
                    dst[3072]   = f2bf(v.w);
                }
            }
        }
    }
}

// ---------------------------------------------------------------------------
// Kernel 3: MFMA attention, K/V LDS-resident, 16 waves (4/SIMD) for TLP.
// Block = (b, h, n-half): 256 blocks (1/CU), 1024 thr = 16 waves, wave owns
// 2 q-tiles (32 rows). K (64KB) + V (64KB) staged once via global_load_lds;
// per-wave S-tile 16x64 (2KB, 32KB total) -> LDS exactly 160 KB.
// Key loop: 16 tiles of 64 keys; K/V frags hoisted per tile, shared by both
// q-tiles. Swizzles (XOR involutions; staged via pre-swizzled GLOBAL source
// since global_load_lds writes linearly):
//   K u16 idx ^= ((idx>>6)&3)<<3, V u16 idx ^= ((idx>>10)&7)<<3,
//   S row off ^= (q&7)<<3  -> writes 2-way (free), b128 reads conflict-free.
// Bias from permuted biasP (one coalesced 8B load/lane per key-block).
// One barrier total. XCD map: (flat&7)*32+flat>>3 -> batches {2k,2k+1}/XCD.
// ---------------------------------------------------------------------------
__global__ __launch_bounds__(1024, 4) void attn_mfma(
    const unsigned short* __restrict__ Qbf, const unsigned short* __restrict__ Kbf,
    const unsigned short* __restrict__ Vt, const unsigned short* __restrict__ biasP,
    unsigned short* __restrict__ O16)
{
    const int flat = blockIdx.x;
    const int id2  = (flat & 7) * 32 + (flat >> 3);   // bijective, 256 % 8 == 0
    const int b    = id2 >> 4;
    const int h    = (id2 >> 1) & 7;
    const int nh   = id2 & 1;

    const int t = threadIdx.x;
    const int w = t >> 6;            // wave 0..15
    const int lane = t & 63;
    const int col = lane & 15;
    const int quad = lane >> 4;

    __shared__ unsigned short Klds[32768];     // 64 KB  [1024][32] swizzled
    __shared__ unsigned short Vlds[32768];     // 64 KB  [32][1024] swizzled
    __shared__ unsigned short S16[16][1024];   // 32 KB, 2 KB per wave

    const size_t hb = (size_t)b * Hq + h;
    const unsigned short* Qh = Qbf + hb * (Nq * HDq);
    const unsigned short* Kh = Kbf + hb * (Nq * HDq);
    const unsigned short* Vh = Vt  + hb * (HDq * Nq);

    // ---- stage K,V -> LDS (linear dest, inverse-swizzled source)
    #pragma unroll
    for (int i = 0; i < 4; i++) {
        const int ck = i * 1024 + t;                   // 16B chunk id, 0..4095
        async16(&Klds[ck * 8], Kh + ((ck * 8) ^ (((ck >> 3) & 3) << 3)));
        async16(&Vlds[ck * 8], Vh + ((ck * 8) ^ (((ck >> 7) & 7) << 3)));
    }

    // ---- Q rows for my 2 q-tiles (independent of staging)
    const int n0 = nh * 512 + w * 32;
    short8 aq[2];
    #pragma unroll
    for (int qt = 0; qt < 2; qt++)
        aq[qt] = *(const short8*)(Qh + (size_t)(n0 + qt * 16 + col) * HDq + quad * 8);

    const unsigned short* Ps0 = biasP + ((size_t)(b * 64 + nh * 32 + w * 2) << 14);
    unsigned short* Sw = &S16[w][0];

    __syncthreads();   // staging complete — the only barrier

    f32x4 o0[2] = {{0.f,0.f,0.f,0.f},{0.f,0.f,0.f,0.f}};
    f32x4 o1[2] = {{0.f,0.f,0.f,0.f},{0.f,0.f,0.f,0.f}};
    float rsum[2][4] = {};

    for (int tt = 0; tt < 16; tt++) {                  // 64-key tiles
        const int k0 = tt * 64;
        // K/V fragments for this tile: shared by both q-tiles
        short8 kf[4], vf0[2], vf1[2];
        #pragma unroll
        for (int m = 0; m < 4; m++)
            kf[m] = *(const short8*)&Klds[((k0 + m * 16 + col) * 32 + quad * 8)
                                          ^ (((col >> 1) & 3) << 3)];
        #pragma unroll
        for (int c = 0; c < 2; c++) {
            vf0[c] = *(const short8*)&Vlds[((col << 10) + k0 + c * 32 + quad * 8)
                                           ^ ((col & 7) << 3)];
            vf1[c] = *(const short8*)&Vlds[(((col + 16) << 10) + k0 + c * 32 + quad * 8)
                                           ^ ((col & 7) << 3)];
        }
        #pragma unroll
        for (int qt = 0; qt < 2; qt++) {
            const unsigned short* Psq = Ps0 + (qt << 14) + (k0 << 4);
            // ---- QK^T + bias + exp -> per-wave swizzled S-tile
            #pragma unroll
            for (int m = 0; m < 4; m++) {
                f32x4 cc = {0.f, 0.f, 0.f, 0.f};
                cc = __builtin_amdgcn_mfma_f32_16x16x32_bf16(aq[qt], kf[m], cc, 0, 0, 0);
                uint2 bv = *(const uint2*)(Psq + (m << 8) + col * 16 + quad * 4);
                const float bi[4] = {
                    bf2f((unsigned short)(bv.x & 0xffff)), bf2f((unsigned short)(bv.x >> 16)),
                    bf2f((unsigned short)(bv.y & 0xffff)), bf2f((unsigned short)(bv.y >> 16))
                };
                #pragma unroll
                for (int i = 0; i < 4; i++) {
                    const int r = quad * 4 + i;
                    float e = __expf(cc[i] + bi[i]);
                    rsum[qt][i] += e;
                    const int sidx = (r * 64 + m * 16 + col) ^ ((r & 7) << 3);
                    Sw[sidx] = f2bf(e);
                }
            }
            // ---- PV: S-tile @ V (same-wave LDS RAW; compiler inserts waits)
            #pragma unroll
            for (int c = 0; c < 2; c++) {
                const int ridx = (col * 64 + c * 32 + quad * 8) ^ ((col & 7) << 3);
                short8 ap = *(const short8*)&Sw[ridx];
                o0[qt] = __builtin_amdgcn_mfma_f32_16x16x32_bf16(ap, vf0[c], o0[qt], 0, 0, 0);
                o1[qt] = __builtin_amdgcn_mfma_f32_16x16x32_bf16(ap, vf1[c], o1[qt], 0, 0, 0);
            }
        }
    }

    // ---- row-sum reduce (16 col-lanes per quad) + normalize + store
    #pragma unroll
    for (int qt = 0; qt < 2; qt++) {
        #pragma unroll
        for (int off = 1; off < 16; off <<= 1) {
            #pragma unroll
            for (int i = 0; i < 4; i++) rsum[qt][i] += __shfl_xor(rsum[qt][i], off, 16);
        }
        unsigned short* op = O16 + ((size_t)b * Nq + n0 + qt * 16) * Dq + h * HDq;
        #pragma unroll
        for (int i = 0; i < 4; i++) {
            const float inv = 1.0f / rsum[qt][i];
            const int q = quad * 4 + i;
            op[(size_t)q * Dq + col]      = f2bf(o0[qt][i] * inv);
            op[(size_t)q * Dq + col + 16] = f2bf(o1[qt][i] * inv);
        }
    }
}

// ---------------------------------------------------------------------------
// Kernel 4: pad_mask2 — zero rows of out where att_output has any exact 0
// ---------------------------------------------------------------------------
__global__ __launch_bounds__(256) void pad2_kernel(
    const float* __restrict__ AO, float* __restrict__ out)
{
    const int row = blockIdx.x;
    const int t = threadIdx.x;
    const float v = AO[(size_t)row * Dq + t];
    unsigned long long m = __ballot(v == 0.0f);
    __shared__ unsigned long long w[4];
    if ((t & 63) == 0) w[t >> 6] = m;
    __syncthreads();
    if ((w[0] | w[1] | w[2] | w[3]) != 0ULL)
        out[(size_t)row * Dq + t] = 0.0f;
}

// ---------------------------------------------------------------------------
extern "C" void kernel_launch(void* const* d_in, const int* in_sizes, int n_in,
                              void* d_out, int out_size, void* d_ws, size_t ws_size,
                              hipStream_t stream)
{
    const float* x      = (const float*)d_in[0];
    const float* sp     = (const float*)d_in[1];
    const float* ed     = (const float*)d_in[2];
    const float* gamma1 = (const float*)d_in[3];
    const float* beta1  = (const float*)d_in[4];
    const float* gamma2 = (const float*)d_in[5];
    const float* beta2  = (const float*)d_in[6];
    const float* Wq     = (const float*)d_in[7];
    const float* Wk     = (const float*)d_in[8];
    const float* Wv     = (const float*)d_in[9];
    const float* Wo     = (const float*)d_in[10];
    const float* W1     = (const float*)d_in[11];
    const float* b1     = (const float*)d_in[12];
    const float* W2     = (const float*)d_in[13];
    const float* b2     = (const float*)d_in[14];
    float* out = (float*)d_out;

    // workspace layout (in shorts)
    unsigned short* s = (unsigned short*)d_ws;
    const size_t MD = (size_t)Mq * Dq;                  // 4.19M elements
    unsigned short* att_in16 = s;                        // [M,D] bf16; reused as O16
    unsigned short* ffn_in16 = s + MD;                   // [M,D] bf16
    unsigned short* Qbf      = s + 2 * MD;               // [B,H,N,32] bf16
    unsigned short* Kbf      = s + 3 * MD;               // [B,H,N,32] bf16
    unsigned short* Vtb      = s + 4 * MD;               // [B,H,32,N] bf16 (transposed)
    unsigned short* W16      = s + 5 * MD;               // 786432 shorts
    unsigned short* h16      = s + 5 * MD + 786432;      // [M,F] bf16 (33.5 MB)
    unsigned short* O16      = att_in16;                 // attn out (att_in dead)
    float*          AO       = (float*)Qbf;              // [M,D] fp32 (Q/K dead)
    // biasP [B][64][64][16][16] bf16 = 16.78M shorts == exactly h16's size;
    // biasP is dead before FFN1 writes h16 -> alias them (no extra workspace).
    unsigned short* biasP    = h16;

    unsigned short* Wo16 = W16 + 196608;
    unsigned short* W116 = W16 + 262144;
    unsigned short* W216 = W16 + 524288;

    // 0) weights -> bf16 (Wq/Wk/Wv contiguous as rows 0..767 for merged QKV)
    cvt_weights<<<768, 256, 0, stream>>>(Wq, Wk, Wv, Wo, W1, W2, W16);

    // 0b) biasP = bf16(sp + ed) in MFMA-fragment-permuted layout
    bias_cvt_perm<<<dim3(64, 16), 256, 0, stream>>>(sp, ed, biasP);

    // 1) both layernorms -> bf16
    ln2_kernel<<<Mq, 256, 0, stream>>>(x, gamma1, beta1, gamma2, beta2, att_in16, ffn_in16);

    // 2) merged QKV projection (Q scaled + head-major, K head-major, V transposed)
    dim3 gQKV(768 / TN, Mq / TM);   // (6, 128)
    gemm_mfma<<<gQKV, 256, 0, stream>>>(att_in16, W16, nullptr, nullptr, nullptr, nullptr,
                                        Qbf, Kbf, Vtb, Mq, 768, Dq, 2, 0);

    // 3) attention: 256 blocks = (b, h, n-half), K/V LDS-resident, 16 waves
    attn_mfma<<<256, 1024, 0, stream>>>(Qbf, Kbf, Vtb, biasP, O16);

    // 4) output projection + residual: AO = O @ Wo^T + x   (fp32)
    dim3 gP(Dq / TN, Mq / TM);
    gemm_mfma<<<gP, 256, 0, stream>>>(O16, Wo16, nullptr, x, AO, nullptr,
                                      nullptr, nullptr, nullptr, Mq, Dq, Dq, 0, 0);

    // 5) FFN1: h16 = bf16(gelu(ffn_in @ W1^T + b1))
    dim3 gF1(Fq / TN, Mq / TM);
    gemm_mfma<<<gF1, 256, 0, stream>>>(ffn_in16, W116, b1, nullptr, nullptr, h16,
                                       nullptr, nullptr, nullptr, Mq, Fq, Dq, 1, 1);

    // 6) FFN2: out = h @ W2^T + b2 + AO
    gemm_mfma<<<gP, 256, 0, stream>>>(h16, W216, b2, AO, out, nullptr,
                                      nullptr, nullptr, nullptr, Mq, Dq, Fq, 0, 0);

    // 7) pad_mask2 row zeroing
    pad2_kernel<<<Mq, 256, 0, stream>>>(AO, out);
}

// Round 6
// 381.843 us; speedup vs baseline: 1.3687x; 1.0104x over previous
//
#include <hip/hip_runtime.h>
#include <hip/hip_bf16.h>
#include <math.h>

// Problem constants (B=16, N=1024, D=256, F=1024, H=8, hd=32)
#define Bq 16
#define Nq 1024
#define Dq 256
#define Fq 1024
#define Hq 8
#define HDq 32
#define Mq (Bq * Nq)          // 16384 rows
#define SCALE 0.0625f          // D^-0.5 = 1/16
#define LN_EPS 1e-5f

typedef __attribute__((ext_vector_type(8))) short short8;   // 8 bf16
typedef __attribute__((ext_vector_type(4))) float f32x4;

__device__ __forceinline__ float bf2f(unsigned short s) {
    unsigned u = ((unsigned)s) << 16;
    return __builtin_bit_cast(float, u);
}
__device__ __forceinline__ unsigned short f2bf(float f) {
    __hip_bfloat16 h = __float2bfloat16(f);
    return __builtin_bit_cast(unsigned short, h);
}

// async global->LDS, 16B per lane (lands at ldsbase + lane*16)
typedef __attribute__((address_space(3))) unsigned int lds_uint;
typedef const __attribute__((address_space(1))) unsigned int glb_uint;
__device__ __forceinline__ void async16(void* lds, const void* g) {
    __builtin_amdgcn_global_load_lds((glb_uint*)g, (lds_uint*)lds, 16, 0, 0);
}

__device__ __forceinline__ float gelu_tanh(float v) {
    const float c = 0.7978845608028654f;
    float u = c * (v + 0.044715f * v * v * v);
    return 0.5f * v * (1.0f + tanhf(u));
}

// ---------------------------------------------------------------------------
// Kernel 0: convert the 6 weight matrices to bf16 (Wq,Wk,Wv rows 0..767 of W16)
// ---------------------------------------------------------------------------
__global__ __launch_bounds__(256) void cvt_weights(
    const float* __restrict__ Wq, const float* __restrict__ Wk,
    const float* __restrict__ Wv, const float* __restrict__ Wo,
    const float* __restrict__ W1, const float* __restrict__ W2,
    unsigned short* __restrict__ dst)
{
    const int blk = blockIdx.x;
    int seg, local;
    if (blk < 256)      { seg = blk >> 6; local = blk & 63; }
    else if (blk < 512) { seg = 4; local = blk - 256; }
    else                { seg = 5; local = blk - 512; }
    const float* srcs[6] = {Wq, Wk, Wv, Wo, W1, W2};
    const size_t dsto[6] = {0, 65536, 131072, 196608, 262144, 524288};
    const float* src = srcs[seg] + (size_t)local * 1024;
    unsigned short* d = dst + dsto[seg] + (size_t)local * 1024;
    const int t4 = threadIdx.x * 4;
    float4 v = *(const float4*)(src + t4);
    uint2 o;
    o.x = (unsigned)f2bf(v.x) | ((unsigned)f2bf(v.y) << 16);
    o.y = (unsigned)f2bf(v.z) | ((unsigned)f2bf(v.w) << 16);
    *(uint2*)(d + t4) = o;
}

// ---------------------------------------------------------------------------
// Kernel 0b: bias -> bf16 in MFMA-fragment-permuted layout.
// P[b][nt][mq][col][r]  (dims 16,64,64,16,16; r fastest), mq = key-block 0..63
// so the attn wave's per-key-block bias read is ONE coalesced 8B load/lane.
// v2: column-split blocks (grid 128x16 = 2048 blocks -> 8 blocks/CU, 100%
// wave occupancy), bf16 convert BEFORE LDS (uint2 stores, shorter dep chain,
// half the LDS bytes), 16.5 KB LDS (stride 516 shorts: transpose reads are
// 2-lane same-address broadcasts -> conflict-free), 8 fully-unrolled
// independent read iters for deep load pipelining.
// ---------------------------------------------------------------------------
__global__ __launch_bounds__(256) void bias_cvt_perm(
    const float* __restrict__ sp, const float* __restrict__ ed,
    unsigned short* __restrict__ P)
{
    const int bx = blockIdx.x;           // 0..127
    const int cx = bx & 1;               // column half
    const int nt = bx >> 1;              // q-row tile 0..63
    const int b  = blockIdx.y;
    const int t  = threadIdx.x;
    __shared__ unsigned short lds[16][516];   // 16.5 KB (+4 pad/row)
    const size_t src0 = ((size_t)b * Nq + nt * 16) * Nq + cx * 512;

    #pragma unroll
    for (int it = 0; it < 8; it++) {
        const int idx = it * 256 + t;            // 0..2047
        const int r = idx >> 7;                  // row 0..15
        const int c4 = (idx & 127) * 4;          // col 0..508
        float4 a = *(const float4*)(sp + src0 + (size_t)r * Nq + c4);
        float4 e = *(const float4*)(ed + src0 + (size_t)r * Nq + c4);
        uint2 o;
        o.x = (unsigned)f2bf(a.x + e.x) | ((unsigned)f2bf(a.y + e.y) << 16);
        o.y = (unsigned)f2bf(a.z + e.z) | ((unsigned)f2bf(a.w + e.w) << 16);
        *(uint2*)&lds[r][c4] = o;
    }
    __syncthreads();

    unsigned short* Ps = P + ((size_t)(b * 64 + nt) << 14) + cx * 8192;
    #pragma unroll
    for (int it = 0; it < 4; it++) {
        const int oo  = (it * 256 + t) * 8;      // 0..8191
        const int r0  = oo & 15;                 // 0 or 8
        const int col = (oo >> 4) & 15;
        const int mql = oo >> 8;                 // local key-block 0..31
        const int c   = mql * 16 + col;
        uint4 w;
        w.x = (unsigned)lds[r0 + 0][c] | ((unsigned)lds[r0 + 1][c] << 16);
        w.y = (unsigned)lds[r0 + 2][c] | ((unsigned)lds[r0 + 3][c] << 16);
        w.z = (unsigned)lds[r0 + 4][c] | ((unsigned)lds[r0 + 5][c] << 16);
        w.w = (unsigned)lds[r0 + 6][c] | ((unsigned)lds[r0 + 7][c] << 16);
        *(uint4*)(Ps + oo) = w;
    }
}

// ---------------------------------------------------------------------------
// Kernel 1: fused double LayerNorm -> bf16 outputs (shared mean/rstd)
// ---------------------------------------------------------------------------
__global__ __launch_bounds__(256) void ln2_kernel(
    const float* __restrict__ x,
    const float* __restrict__ g1, const float* __restrict__ bb1,
    const float* __restrict__ g2, const float* __restrict__ bb2,
    unsigned short* __restrict__ att_in, unsigned short* __restrict__ ffn_in)
{
    const int row = blockIdx.x;
    const int t = threadIdx.x;
    const size_t base = (size_t)row * Dq;
    float v = x[base + t];

    float s = v, sq = v * v;
    #pragma unroll
    for (int off = 32; off > 0; off >>= 1) {
        s  += __shfl_down(s, off);
        sq += __shfl_down(sq, off);
    }
    __shared__ float ssum[4], ssq[4];
    __shared__ float mu_s, rstd_s;
    const int lane = t & 63, wid = t >> 6;
    if (lane == 0) { ssum[wid] = s; ssq[wid] = sq; }
    __syncthreads();
    if (t == 0) {
        float S = ssum[0] + ssum[1] + ssum[2] + ssum[3];
        float Q = ssq[0] + ssq[1] + ssq[2] + ssq[3];
        float mu = S * (1.0f / Dq);
        float var = Q * (1.0f / Dq) - mu * mu;
        mu_s = mu;
        rstd_s = rsqrtf(var + LN_EPS);
    }
    __syncthreads();
    const float nx = (v - mu_s) * rstd_s;
    att_in[base + t] = f2bf(nx * g1[t] + bb1[t]);
    ffn_in[base + t] = f2bf(nx * g2[t] + bb2[t]);
}

// ---------------------------------------------------------------------------
// Kernel 2: MFMA NT GEMM  C[M,Nc] = A[M,K] * W[Nc,K]^T  (bf16 in, fp32 acc)
// 128x128 tile, BK=32, DOUBLE-BUFFERED prefetch (T3 minimum 2-phase): next
// K-step's global_load_lds issues into buf^1 BEFORE computing buf, so HBM/L2
// load latency hides under MFMA + frag reads; one barrier per K-step (was 2).
// mode 0: fp32 out (+bias,+gelu,+add)   [Wo, FFN2]
// mode 1: bf16 flat out (+bias,+gelu)   [FFN1]
// mode 2: merged QKV (Nc=768): Q scaled+head-major, K head-major, V transposed
// ---------------------------------------------------------------------------
#define TM 128
#define TN 128
#define TK 32

__global__ __launch_bounds__(256) void gemm_mfma(
    const unsigned short* __restrict__ A, const unsigned short* __restrict__ W,
    const float* __restrict__ bias, const float* __restrict__ add,
    float* __restrict__ outF, unsigned short* __restrict__ outBF,
    unsigned short* __restrict__ Qb, unsigned short* __restrict__ Kb,
    unsigned short* __restrict__ Vt,
    int M, int Nc, int K, int mode, int apply_gelu)
{
    __shared__ unsigned short As[2][TM * TK];   // 2 x 8 KB
    __shared__ unsigned short Bs[2][TN * TK];   // 2 x 8 KB
    const int t = threadIdx.x;
    const int w = t >> 6, lane = t & 63;
    const int col = lane & 15, quad = lane >> 4;
    const int wr = w >> 1, wc = w & 1;
    const int row0 = blockIdx.y * TM;
    const int col0 = blockIdx.x * TN;

    f32x4 acc[4][4] = {};

    // per-thread staging geometry (wave-uniform LDS base; lane scatters x16B)
    const int c0s = w * 128 + lane;          // chunk for j=0
    const int c1s = c0s + 64;                // chunk for j=1
    const int r0s = c0s >> 2, s0s = (c0s & 3) * 8;
    const int r1s = c1s >> 2, s1s = (c1s & 3) * 8;

#define STAGE(buf, kk)                                                        \
    do {                                                                      \
        async16(&As[buf][(w * 128) * 8],      A + (size_t)(row0 + r0s) * K + (kk) + s0s); \
        async16(&Bs[buf][(w * 128) * 8],      W + (size_t)(col0 + r0s) * K + (kk) + s0s); \
        async16(&As[buf][(w * 128 + 64) * 8], A + (size_t)(row0 + r1s) * K + (kk) + s1s); \
        async16(&Bs[buf][(w * 128 + 64) * 8], W + (size_t)(col0 + r1s) * K + (kk) + s1s); \
    } while (0)

    STAGE(0, 0);
    __syncthreads();   // buf0 staged

    int cur = 0;
    for (int k0 = 0; k0 < K; k0 += TK) {
        if (k0 + TK < K) STAGE(cur ^ 1, k0 + TK);   // prefetch next (async)
        short8 wf[4], af[4];
        #pragma unroll
        for (int i = 0; i < 4; i++)
            wf[i] = *(const short8*)&Bs[cur][(wc * 64 + i * 16 + col) * TK + quad * 8];
        #pragma unroll
        for (int j = 0; j < 4; j++)
            af[j] = *(const short8*)&As[cur][(wr * 64 + j * 16 + col) * TK + quad * 8];
        // D[c][r]: A-operand = W rows (c), B-operand = A rows (r)
        #pragma unroll
        for (int i = 0; i < 4; i++)
            #pragma unroll
            for (int j = 0; j < 4; j++)
                acc[i][j] = __builtin_amdgcn_mfma_f32_16x16x32_bf16(wf[i], af[j], acc[i][j], 0, 0, 0);
        __syncthreads();   // drains prefetch (vmcnt) + frag reads; swap safe
        cur ^= 1;
    }
#undef STAGE

    // epilogue: lane owns cols c0..c0+3 (consecutive), output row r
    #pragma unroll
    for (int i = 0; i < 4; i++) {
        #pragma unroll
        for (int j = 0; j < 4; j++) {
            const int c0 = col0 + wc * 64 + i * 16 + quad * 4;
            const int r  = row0 + wr * 64 + j * 16 + col;
            float4 v = make_float4(acc[i][j][0], acc[i][j][1], acc[i][j][2], acc[i][j][3]);
            if (mode == 2 && c0 < 256) { v.x *= SCALE; v.y *= SCALE; v.z *= SCALE; v.w *= SCALE; }
            if (bias) {
                float4 bb = *(const float4*)&bias[c0];
                v.x += bb.x; v.y += bb.y; v.z += bb.z; v.w += bb.w;
            }
            if (apply_gelu) {
                v.x = gelu_tanh(v.x); v.y = gelu_tanh(v.y);
                v.z = gelu_tanh(v.z); v.w = gelu_tanh(v.w);
            }
            if (add) {
                float4 aa = *(const float4*)&add[(size_t)r * Nc + c0];
                v.x += aa.x; v.y += aa.y; v.z += aa.z; v.w += aa.w;
            }
            if (mode == 0) {
                *(float4*)&outF[(size_t)r * Nc + c0] = v;
            } else if (mode == 1) {
                uint2 o;
                o.x = (unsigned)f2bf(v.x) | ((unsigned)f2bf(v.y) << 16);
                o.y = (unsigned)f2bf(v.z) | ((unsigned)f2bf(v.w) << 16);
                *(uint2*)&outBF[(size_t)r * Nc + c0] = o;
            } else {
                const int b = r >> 10, n = r & 1023;
                if (c0 < 512) {
                    // Q (c0<256, pre-scaled) or K: head-major [B,H,N,32]
                    const int cq = c0 & 255;
                    const int h = cq >> 5, d0 = cq & 31;
                    unsigned short* dst = (c0 < 256 ? Qb : Kb);
                    uint2 o;
                    o.x = (unsigned)f2bf(v.x) | ((unsigned)f2bf(v.y) << 16);
                    o.y = (unsigned)f2bf(v.z) | ((unsigned)f2bf(v.w) << 16);
                    *(uint2*)&dst[(((size_t)(b * Hq + h) << 10) + n) * HDq + d0] = o;
                } else {
                    // V transposed: Vt[B,H,32,N]
                    const int cv = c0 - 512;
                    const int h = cv >> 5, d0 = cv & 31;
                    unsigned short* dst = Vt + (((size_t)(b * Hq + h) * HDq + d0) << 10) + n;
                    dst[0]      = f2bf(v.x);
                    dst[1024]   = f2bf(v.y);
                    dst[2048]   = f2bf(v.z);
                    dst[3072]   = f2bf(v.w);
                }
            }
        }
    }
}

// ---------------------------------------------------------------------------
// Kernel 3: MFMA attention, K/V LDS-resident, 16 waves (4/SIMD) for TLP.
// Block = (b, h, n-half): 256 blocks (1/CU), 1024 thr = 16 waves, wave owns
// 2 q-tiles (32 rows). K (64KB) + V (64KB) staged once via global_load_lds;
// per-wave S-tile 16x64 (2KB, 32KB total) -> LDS exactly 160 KB.
// Key loop: 16 tiles of 64 keys; K/V frags hoisted per tile, shared by both
// q-tiles. Swizzles (XOR involutions; staged via pre-swizzled GLOBAL source
// since global_load_lds writes linearly):
//   K u16 idx ^= ((idx>>6)&3)<<3, V u16 idx ^= ((idx>>10)&7)<<3,
//   S row off ^= (q&7)<<3  -> writes 2-way (free), b128 reads conflict-free.
// Bias from permuted biasP (one coalesced 8B load/lane per key-block).
// One barrier total. XCD map: (flat&7)*32+flat>>3 -> batches {2k,2k+1}/XCD.
// ---------------------------------------------------------------------------
__global__ __launch_bounds__(1024, 4) void attn_mfma(
    const unsigned short* __restrict__ Qbf, const unsigned short* __restrict__ Kbf,
    const unsigned short* __restrict__ Vt, const unsigned short* __restrict__ biasP,
    unsigned short* __restrict__ O16)
{
    const int flat = blockIdx.x;
    const int id2  = (flat & 7) * 32 + (flat >> 3);   // bijective, 256 % 8 == 0
    const int b    = id2 >> 4;
    const int h    = (id2 >> 1) & 7;
    const int nh   = id2 & 1;

    const int t = threadIdx.x;
    const int w = t >> 6;            // wave 0..15
    const int lane = t & 63;
    const int col = lane & 15;
    const int quad = lane >> 4;

    __shared__ unsigned short Klds[32768];     // 64 KB  [1024][32] swizzled
    __shared__ unsigned short Vlds[32768];     // 64 KB  [32][1024] swizzled
    __shared__ unsigned short S16[16][1024];   // 32 KB, 2 KB per wave

    const size_t hb = (size_t)b * Hq + h;
    const unsigned short* Qh = Qbf + hb * (Nq * HDq);
    const unsigned short* Kh = Kbf + hb * (Nq * HDq);
    const unsigned short* Vh = Vt  + hb * (HDq * Nq);

    // ---- stage K,V -> LDS (linear dest, inverse-swizzled source)
    #pragma unroll
    for (int i = 0; i < 4; i++) {
        const int ck = i * 1024 + t;                   // 16B chunk id, 0..4095
        async16(&Klds[ck * 8], Kh + ((ck * 8) ^ (((ck >> 3) & 3) << 3)));
        async16(&Vlds[ck * 8], Vh + ((ck * 8) ^ (((ck >> 7) & 7) << 3)));
    }

    // ---- Q rows for my 2 q-tiles (independent of staging)
    const int n0 = nh * 512 + w * 32;
    short8 aq[2];
    #pragma unroll
    for (int qt = 0; qt < 2; qt++)
        aq[qt] = *(const short8*)(Qh + (size_t)(n0 + qt * 16 + col) * HDq + quad * 8);

    const unsigned short* Ps0 = biasP + ((size_t)(b * 64 + nh * 32 + w * 2) << 14);
    unsigned short* Sw = &S16[w][0];

    __syncthreads();   // staging complete — the only barrier

    f32x4 o0[2] = {{0.f,0.f,0.f,0.f},{0.f,0.f,0.f,0.f}};
    f32x4 o1[2] = {{0.f,0.f,0.f,0.f},{0.f,0.f,0.f,0.f}};
    float rsum[2][4] = {};

    for (int tt = 0; tt < 16; tt++) {                  // 64-key tiles
        const int k0 = tt * 64;
        // K/V fragments for this tile: shared by both q-tiles
        short8 kf[4], vf0[2], vf1[2];
        #pragma unroll
        for (int m = 0; m < 4; m++)
            kf[m] = *(const short8*)&Klds[((k0 + m * 16 + col) * 32 + quad * 8)
                                          ^ (((col >> 1) & 3) << 3)];
        #pragma unroll
        for (int c = 0; c < 2; c++) {
            vf0[c] = *(const short8*)&Vlds[((col << 10) + k0 + c * 32 + quad * 8)
                                           ^ ((col & 7) << 3)];
            vf1[c] = *(const short8*)&Vlds[(((col + 16) << 10) + k0 + c * 32 + quad * 8)
                                           ^ ((col & 7) << 3)];
        }
        #pragma unroll
        for (int qt = 0; qt < 2; qt++) {
            const unsigned short* Psq = Ps0 + (qt << 14) + (k0 << 4);
            // ---- QK^T + bias + exp -> per-wave swizzled S-tile
            #pragma unroll
            for (int m = 0; m < 4; m++) {
                f32x4 cc = {0.f, 0.f, 0.f, 0.f};
                cc = __builtin_amdgcn_mfma_f32_16x16x32_bf16(aq[qt], kf[m], cc, 0, 0, 0);
                uint2 bv = *(const uint2*)(Psq + (m << 8) + col * 16 + quad * 4);
                const float bi[4] = {
                    bf2f((unsigned short)(bv.x & 0xffff)), bf2f((unsigned short)(bv.x >> 16)),
                    bf2f((unsigned short)(bv.y & 0xffff)), bf2f((unsigned short)(bv.y >> 16))
                };
                #pragma unroll
                for (int i = 0; i < 4; i++) {
                    const int r = quad * 4 + i;
                    float e = __expf(cc[i] + bi[i]);
                    rsum[qt][i] += e;
                    const int sidx = (r * 64 + m * 16 + col) ^ ((r & 7) << 3);
                    Sw[sidx] = f2bf(e);
                }
            }
            // ---- PV: S-tile @ V (same-wave LDS RAW; compiler inserts waits)
            #pragma unroll
            for (int c = 0; c < 2; c++) {
                const int ridx = (col * 64 + c * 32 + quad * 8) ^ ((col & 7) << 3);
                short8 ap = *(const short8*)&Sw[ridx];
                o0[qt] = __builtin_amdgcn_mfma_f32_16x16x32_bf16(ap, vf0[c], o0[qt], 0, 0, 0);
                o1[qt] = __builtin_amdgcn_mfma_f32_16x16x32_bf16(ap, vf1[c], o1[qt], 0, 0, 0);
            }
        }
    }

    // ---- row-sum reduce (16 col-lanes per quad) + normalize + store
    #pragma unroll
    for (int qt = 0; qt < 2; qt++) {
        #pragma unroll
        for (int off = 1; off < 16; off <<= 1) {
            #pragma unroll
            for (int i = 0; i < 4; i++) rsum[qt][i] += __shfl_xor(rsum[qt][i], off, 16);
        }
        unsigned short* op = O16 + ((size_t)b * Nq + n0 + qt * 16) * Dq + h * HDq;
        #pragma unroll
        for (int i = 0; i < 4; i++) {
            const float inv = 1.0f / rsum[qt][i];
            const int q = quad * 4 + i;
            op[(size_t)q * Dq + col]      = f2bf(o0[qt][i] * inv);
            op[(size_t)q * Dq + col + 16] = f2bf(o1[qt][i] * inv);
        }
    }
}

// ---------------------------------------------------------------------------
// Kernel 4: pad_mask2 — zero rows of out where att_output has any exact 0
// ---------------------------------------------------------------------------
__global__ __launch_bounds__(256) void pad2_kernel(
    const float* __restrict__ AO, float* __restrict__ out)
{
    const int row = blockIdx.x;
    const int t = threadIdx.x;
    const float v = AO[(size_t)row * Dq + t];
    unsigned long long m = __ballot(v == 0.0f);
    __shared__ unsigned long long w[4];
    if ((t & 63) == 0) w[t >> 6] = m;
    __syncthreads();
    if ((w[0] | w[1] | w[2] | w[3]) != 0ULL)
        out[(size_t)row * Dq + t] = 0.0f;
}

// ---------------------------------------------------------------------------
extern "C" void kernel_launch(void* const* d_in, const int* in_sizes, int n_in,
                              void* d_out, int out_size, void* d_ws, size_t ws_size,
                              hipStream_t stream)
{
    const float* x      = (const float*)d_in[0];
    const float* sp     = (const float*)d_in[1];
    const float* ed     = (const float*)d_in[2];
    const float* gamma1 = (const float*)d_in[3];
    const float* beta1  = (const float*)d_in[4];
    const float* gamma2 = (const float*)d_in[5];
    const float* beta2  = (const float*)d_in[6];
    const float* Wq     = (const float*)d_in[7];
    const float* Wk     = (const float*)d_in[8];
    const float* Wv     = (const float*)d_in[9];
    const float* Wo     = (const float*)d_in[10];
    const float* W1     = (const float*)d_in[11];
    const float* b1     = (const float*)d_in[12];
    const float* W2     = (const float*)d_in[13];
    const float* b2     = (const float*)d_in[14];
    float* out = (float*)d_out;

    // workspace layout (in shorts)
    unsigned short* s = (unsigned short*)d_ws;
    const size_t MD = (size_t)Mq * Dq;                  // 4.19M elements
    unsigned short* att_in16 = s;                        // [M,D] bf16; reused as O16
    unsigned short* ffn_in16 = s + MD;                   // [M,D] bf16
    unsigned short* Qbf      = s + 2 * MD;               // [B,H,N,32] bf16
    unsigned short* Kbf      = s + 3 * MD;               // [B,H,N,32] bf16
    unsigned short* Vtb      = s + 4 * MD;               // [B,H,32,N] bf16 (transposed)
    unsigned short* W16      = s + 5 * MD;               // 786432 shorts
    unsigned short* h16      = s + 5 * MD + 786432;      // [M,F] bf16 (33.5 MB)
    unsigned short* O16      = att_in16;                 // attn out (att_in dead)
    float*          AO       = (float*)Qbf;              // [M,D] fp32 (Q/K dead)
    // biasP [B][64][64][16][16] bf16 = 16.78M shorts == exactly h16's size;
    // biasP is dead before FFN1 writes h16 -> alias them (no extra workspace).
    unsigned short* biasP    = h16;

    unsigned short* Wo16 = W16 + 196608;
    unsigned short* W116 = W16 + 262144;
    unsigned short* W216 = W16 + 524288;

    // 0) weights -> bf16 (Wq/Wk/Wv contiguous as rows 0..767 for merged QKV)
    cvt_weights<<<768, 256, 0, stream>>>(Wq, Wk, Wv, Wo, W1, W2, W16);

    // 0b) biasP = bf16(sp + ed) in MFMA-fragment-permuted layout (v2: 2048 blk)
    bias_cvt_perm<<<dim3(128, 16), 256, 0, stream>>>(sp, ed, biasP);

    // 1) both layernorms -> bf16
    ln2_kernel<<<Mq, 256, 0, stream>>>(x, gamma1, beta1, gamma2, beta2, att_in16, ffn_in16);

    // 2) merged QKV projection (Q scaled + head-major, K head-major, V transposed)
    dim3 gQKV(768 / TN, Mq / TM);   // (6, 128)
    gemm_mfma<<<gQKV, 256, 0, stream>>>(att_in16, W16, nullptr, nullptr, nullptr, nullptr,
                                        Qbf, Kbf, Vtb, Mq, 768, Dq, 2, 0);

    // 3) attention: 256 blocks = (b, h, n-half), K/V LDS-resident, 16 waves
    attn_mfma<<<256, 1024, 0, stream>>>(Qbf, Kbf, Vtb, biasP, O16);

    // 4) output projection + residual: AO = O @ Wo^T + x   (fp32)
    dim3 gP(Dq / TN, Mq / TM);
    gemm_mfma<<<gP, 256, 0, stream>>>(O16, Wo16, nullptr, x, AO, nullptr,
                                      nullptr, nullptr, nullptr, Mq, Dq, Dq, 0, 0);

    // 5) FFN1: h16 = bf16(gelu(ffn_in @ W1^T + b1))
    dim3 gF1(Fq / TN, Mq / TM);
    gemm_mfma<<<gF1, 256, 0, stream>>>(ffn_in16, W116, b1, nullptr, nullptr, h16,
                                       nullptr, nullptr, nullptr, Mq, Fq, Dq, 1, 1);

    // 6) FFN2: out = h @ W2^T + b2 + AO
    gemm_mfma<<<gP, 256, 0, stream>>>(h16, W216, b2, AO, out, nullptr,
                                      nullptr, nullptr, nullptr, Mq, Dq, Fq, 0, 0);

    // 7) pad_mask2 row zeroing
    pad2_kernel<<<Mq, 256, 0, stream>>>(AO, out);
}